// Round 5
// baseline (411.554 us; speedup 1.0000x reference)
//
#include <hip/hip_runtime.h>
#include <math.h>

#define ATT_SCALE 0.17677669529663687f  // 32^-0.5

typedef __bf16 bf16x8 __attribute__((ext_vector_type(8)));
typedef __bf16 bf16x4 __attribute__((ext_vector_type(4)));
typedef float  f32x4  __attribute__((ext_vector_type(4)));

#define MFMA16(a,b,c) __builtin_amdgcn_mfma_f32_16x16x32_bf16(a,b,c,0,0,0)

// ws layout: [0,786432) f32 expanded bias; then bf16 swizzled weights
#define BIAS_BYTES 786432
#define WKV_OFF 0        // 192x384  kt6  NRT24
#define WQ_OFF  73728    // 96x192   kt3  NRT12 (pre-scaled)
#define WP_OFF  92160    // 192x96   kt6  NRT6
#define WD_OFF  110592   // deconv: [ii][kt6][rt24][lane][8], M=384 rows = (jk*96+o)
#define W1_OFF  258048   // 96x384   kt3  NRT24
#define W2_OFF  294912   // 384x96   kt12 NRT6
#define NSWZ    331776

static __device__ __forceinline__ float gelu_exact(float v){
    return 0.5f * v * (1.0f + erff(v * 0.70710678118654752f));
}

static __device__ __forceinline__ bf16x8 afrag(const __bf16* w, int NRT, int kt, int rt, int lane){
    return ((const bf16x8*)w)[(kt*NRT + rt)*64 + lane];
}

// ---------------- prep: bias expand + weight bf16 swizzle ----------------
__global__ __launch_bounds__(256) void k_prep(const float* __restrict__ table,
    const float* __restrict__ Wkv, const float* __restrict__ Wq,
    const float* __restrict__ Wp,  const float* __restrict__ Wd,
    const float* __restrict__ W1,  const float* __restrict__ W2,
    float* __restrict__ bias, __bf16* __restrict__ wsw){
    int id = blockIdx.x * 256 + threadIdx.x;
    if (id < 196608){
        int k  = id & 63;
        int qg = (id >> 6) & 511;
        int h  = id >> 15;
        int qi = qg >> 6, qj = (qg >> 3) & 7, qk = qg & 7;
        int ki = k >> 4,  kj = (k >> 2) & 3,  kk = k & 3;
        int r0 = (qi >> 1) - ki + 3;
        int r1 = (qj >> 1) - kj + 3;
        int r2 = (qk >> 1) - kk + 3;
        bias[id] = table[((r0 * 7 + r1) * 7 + r2) * 6 + h];
        return;
    }
    id -= 196608;
    if (id >= NSWZ) return;
    if (id >= WD_OFF && id < W1_OFF){
        // deconv weights: rows m = jk*96+o (384), K=192, split by ii (deconv i-position)
        int lid  = id - WD_OFF;                    // [0, 147456)
        int j    = lid & 7, lane = (lid >> 3) & 63, tile = lid >> 9;  // tile in [0,288)
        int rt   = tile % 24;
        int kt2  = tile / 24;                      // ii*6 + kt
        int ii   = kt2 / 6, kt = kt2 % 6;
        int n    = rt * 16 + (lane & 15);          // m-index
        int o    = n % 96, jk = n / 96;
        int kdim = kt * 32 + (lane >> 4) * 8 + j;
        wsw[id] = (__bf16)(Wd[(kdim * 96 + o) * 8 + ii * 4 + jk]);
        return;
    }
    const float* W; int N, NRT, off; float sc = 1.f;
    if      (id < WQ_OFF){ W = Wkv; N = 384; NRT = 24; off = WKV_OFF; }
    else if (id < WP_OFF){ W = Wq;  N = 192; NRT = 12; off = WQ_OFF; sc = ATT_SCALE; }
    else if (id < WD_OFF){ W = Wp;  N = 96;  NRT = 6;  off = WP_OFF; }
    else if (id < W2_OFF){ W = W1;  N = 384; NRT = 24; off = W1_OFF; }
    else                 { W = W2;  N = 96;  NRT = 6;  off = W2_OFF; }
    int lid  = id - off;
    int j    = lid & 7, lane = (lid >> 3) & 63, tile = lid >> 9;
    int rt   = tile % NRT, kt = tile / NRT;
    int n    = rt * 16 + (lane & 15);
    int k    = kt * 32 + (lane >> 4) * 8 + j;
    wsw[id + 0] = (__bf16)(W[k * N + n] * sc);
}

// ---------------- fused attn + deconv: d_out = sc + attn (pure store) ----------------
__global__ __launch_bounds__(512) void k_attn(const float* __restrict__ x,
    const float* __restrict__ xd, const float* __restrict__ g1, const float* __restrict__ b1v,
    const float* __restrict__ eg, const float* __restrict__ eb,
    const float* __restrict__ bkv, const float* __restrict__ bq, const float* __restrict__ bpj,
    const float* __restrict__ db,
    const __bf16* __restrict__ wsw, const float* __restrict__ bias, float* __restrict__ yout){
    __shared__ __bf16 Qs[64][196];   // xln -> Q -> attn-out (aliased phases)
    __shared__ __bf16 Ks[64][196];
    __shared__ __bf16 Vt[192][68];   // V transposed [d][kv]
    __shared__ __bf16 Xe[64][200];   // exp-LN of x (deconv input)
    __shared__ float  ysl[64][100];  // deconv slice for current qt (f32)
    const int tid = threadIdx.x, lane = tid & 63, w = tid >> 6;
    const int win = blockIdx.x, b = win >> 8, wrem = win & 255;
    const int sw_ = wrem >> 6, hw_ = (wrem >> 3) & 7, ww_ = wrem & 7;

    {   // stage coarse x window once; write BOTH LN variants (attn-kv + expand)
        int row = tid >> 3, sub = tid & 7;
        int si = row >> 4, hi = (row >> 2) & 3, wi = row & 3;
        int ci = ((b * 16 + 4 * sw_ + si) * 32 + 4 * hw_ + hi) * 32 + 4 * ww_ + wi;
        const float* xp = x + ci * 192 + sub * 24;
        float v[24]; float s = 0.f, ss = 0.f;
        #pragma unroll
        for (int i = 0; i < 6; i++){
            float4 t = ((const float4*)xp)[i];
            v[4*i] = t.x; v[4*i+1] = t.y; v[4*i+2] = t.z; v[4*i+3] = t.w;
            s += t.x + t.y + t.z + t.w;
            ss += t.x*t.x + t.y*t.y + t.z*t.z + t.w*t.w;
        }
        #pragma unroll
        for (int m = 1; m < 8; m <<= 1){ s += __shfl_xor(s, m); ss += __shfl_xor(ss, m); }
        float mu = s * (1.f/192.f), var = ss * (1.f/192.f) - mu*mu, rs = rsqrtf(var + 1e-5f);
        #pragma unroll
        for (int i = 0; i < 3; i++){
            bf16x8 t1, t2;
            #pragma unroll
            for (int jj = 0; jj < 8; jj++){
                int c = sub*24 + 8*i + jj;
                float nv = (v[8*i+jj] - mu) * rs;
                t1[jj] = (__bf16)(nv * g1[c] + b1v[c]);
                t2[jj] = (__bf16)(nv * eg[c] + eb[c]);
            }
            *(bf16x8*)&Qs[row][sub*24 + 8*i] = t1;
            *(bf16x8*)&Xe[row][sub*24 + 8*i] = t2;
        }
    }
    __syncthreads();
    {   // KVproj: KV^T = Wkv^T @ xln^T ; waves 0-3 -> K rows, 4-7 -> V^T
        const int ct = w & 3, rh = w >> 2;
        const int tok = ct * 16 + (lane & 15);
        bf16x8 bfr[6];
        #pragma unroll
        for (int kt = 0; kt < 6; kt++) bfr[kt] = *(const bf16x8*)&Qs[tok][kt*32 + (lane>>4)*8];
        #pragma unroll
        for (int i = 0; i < 12; i++){
            int rt = rh * 12 + i;
            f32x4 acc = {0.f,0.f,0.f,0.f};
            #pragma unroll
            for (int kt = 0; kt < 6; kt++) acc = MFMA16(afrag(wsw + WKV_OFF, 24, kt, rt, lane), bfr[kt], acc);
            int cb = rt * 16 + ((lane >> 4) << 2);
            float4 b4 = *(const float4*)&bkv[cb];
            acc[0] += b4.x; acc[1] += b4.y; acc[2] += b4.z; acc[3] += b4.w;
            if (cb < 192){
                bf16x4 t;
                #pragma unroll
                for (int r = 0; r < 4; r++) t[r] = (__bf16)acc[r];
                *(bf16x4*)&Ks[tok][cb] = t;
            } else {
                #pragma unroll
                for (int r = 0; r < 4; r++) Vt[cb - 192 + r][tok] = (__bf16)acc[r];
            }
        }
    }
    __syncthreads();

    const int li_ = lane & 15, gt_ = lane >> 4, rsel = lane >> 5;

    for (int qt = 0; qt < 8; qt++){
        const int si = qt >> 1, ii = qt & 1;
        {   // P1a: Qproj: Q^T = Wq^T(scaled) @ xd^T ; B-frags straight from global f32
            const int ct = w & 3, rh = w >> 2;
            const int ql = ct * 16 + li_;
            const int ft = ((b * 32 + 8 * sw_ + qt) * 64 + 8 * hw_ + (ql >> 3)) * 64 + 8 * ww_ + (ql & 7);
            bf16x8 bfr[3];
            #pragma unroll
            for (int kt = 0; kt < 3; kt++){
                const float* xp = xd + ft * 96 + kt * 32 + gt_ * 8;
                float4 t0 = *(const float4*)xp;
                float4 t1 = *(const float4*)(xp + 4);
                bf16x8 t;
                t[0]=(__bf16)t0.x; t[1]=(__bf16)t0.y; t[2]=(__bf16)t0.z; t[3]=(__bf16)t0.w;
                t[4]=(__bf16)t1.x; t[5]=(__bf16)t1.y; t[6]=(__bf16)t1.z; t[7]=(__bf16)t1.w;
                bfr[kt] = t;
            }
            #pragma unroll
            for (int i = 0; i < 6; i++){
                int rt = rh * 6 + i;
                f32x4 acc = {0.f,0.f,0.f,0.f};
                #pragma unroll
                for (int kt = 0; kt < 3; kt++) acc = MFMA16(afrag(wsw + WQ_OFF, 12, kt, rt, lane), bfr[kt], acc);
                int cb = rt * 16 + (gt_ << 2);
                float4 b4 = *(const float4*)&bq[cb];
                bf16x4 t;
                t[0] = (__bf16)(acc[0] + b4.x * ATT_SCALE);
                t[1] = (__bf16)(acc[1] + b4.y * ATT_SCALE);
                t[2] = (__bf16)(acc[2] + b4.z * ATT_SCALE);
                t[3] = (__bf16)(acc[3] + b4.w * ATT_SCALE);
                *(bf16x4*)&Qs[ql][cb] = t;
            }
        }
        {   // P1b: deconv slice: C[(jk*96+o)][ctok16] over K=192; -> ysl[fine][o]
            bf16x8 bfrD[6];
            #pragma unroll
            for (int kt = 0; kt < 6; kt++) bfrD[kt] = *(const bf16x8*)&Xe[si*16 + li_][kt*32 + gt_*8];
            const __bf16* wd = wsw + WD_OFF + ii * 73728;
            #pragma unroll
            for (int i = 0; i < 3; i++){
                int rt = w * 3 + i;
                f32x4 acc = {0.f,0.f,0.f,0.f};
                #pragma unroll
                for (int kt = 0; kt < 6; kt++) acc = MFMA16(afrag(wd, 24, kt, rt, lane), bfrD[kt], acc);
                int jk = rt / 6, obase = (rt % 6) * 16 + (gt_ << 2);
                int hi = li_ >> 2, wi = li_ & 3;
                int lql = (2*hi + (jk >> 1)) * 8 + 2*wi + (jk & 1);
                float4 d4 = *(const float4*)&db[obase];
                float4 res;
                res.x = acc[0] + d4.x; res.y = acc[1] + d4.y;
                res.z = acc[2] + d4.z; res.w = acc[3] + d4.w;
                *(float4*)&ysl[lql][obase] = res;
            }
        }
        __syncthreads();
        // P2: scores + softmax + in-register P redistribution + PV
        f32x4 ov[3][2];
        #pragma unroll
        for (int ui = 0; ui < 3; ui++){
            const int u = w * 3 + ui;
            const int h = u >> 2, qct = u & 3;
            f32x4 sc[4];
            __builtin_amdgcn_s_setprio(1);
            #pragma unroll
            for (int rt = 0; rt < 4; rt++){
                bf16x8 a  = *(const bf16x8*)&Ks[rt*16 + li_][h*32 + gt_*8];
                bf16x8 bq8 = *(const bf16x8*)&Qs[qct*16 + li_][h*32 + gt_*8];
                f32x4 z = {0.f,0.f,0.f,0.f};
                sc[rt] = MFMA16(a, bq8, z);
            }
            __builtin_amdgcn_s_setprio(0);
            const int qg = qt * 64 + qct * 16 + li_;
            const float* bp = bias + (h * 512 + qg) * 64 + (gt_ << 2);
            #pragma unroll
            for (int rt = 0; rt < 4; rt++){
                float4 b4 = *(const float4*)(bp + rt * 16);
                sc[rt][0] += b4.x; sc[rt][1] += b4.y; sc[rt][2] += b4.z; sc[rt][3] += b4.w;
            }
            float m = sc[0][0];
            #pragma unroll
            for (int rt = 0; rt < 4; rt++)
                #pragma unroll
                for (int r = 0; r < 4; r++) m = fmaxf(m, sc[rt][r]);
            m = fmaxf(m, __shfl_xor(m, 16));
            m = fmaxf(m, __shfl_xor(m, 32));
            float sum = 0.f;
            #pragma unroll
            for (int rt = 0; rt < 4; rt++)
                #pragma unroll
                for (int r = 0; r < 4; r++){ float e = __expf(sc[rt][r] - m); sc[rt][r] = e; sum += e; }
            sum += __shfl_xor(sum, 16);
            sum += __shfl_xor(sum, 32);
            float inv = 1.f / sum;
            // pack normalized P into bf16 pair words: pwv[rt][h2] covers kv = rt*16+gt*4+2*h2+{0,1}
            unsigned pwv[4][2];
            #pragma unroll
            for (int rt = 0; rt < 4; rt++){
                union { __bf16 hh[2]; unsigned u; } c0, c1;
                c0.hh[0] = (__bf16)(sc[rt][0] * inv); c0.hh[1] = (__bf16)(sc[rt][1] * inv);
                c1.hh[0] = (__bf16)(sc[rt][2] * inv); c1.hh[1] = (__bf16)(sc[rt][3] * inv);
                pwv[rt][0] = c0.u; pwv[rt][1] = c1.u;
            }
            // redistribute C-frag -> B-frag layout
            unsigned bfw[2][4];
            #pragma unroll
            for (int kt = 0; kt < 2; kt++){
                #pragma unroll
                for (int t = 0; t < 4; t++){
                    int gs   = ((gt_ & 1) << 1) + (t >> 1);
                    int addr = (((gs << 4) + li_) << 2);
                    int w0 = __builtin_amdgcn_ds_bpermute(addr, (int)pwv[2*kt + 0][t & 1]);
                    int w1 = __builtin_amdgcn_ds_bpermute(addr, (int)pwv[2*kt + 1][t & 1]);
                    bfw[kt][t] = rsel ? (unsigned)w1 : (unsigned)w0;
                }
            }
            union { unsigned u[4]; bf16x8 v; } pb0, pb1;
            #pragma unroll
            for (int t = 0; t < 4; t++){ pb0.u[t] = bfw[0][t]; pb1.u[t] = bfw[1][t]; }
            __builtin_amdgcn_s_setprio(1);
            #pragma unroll
            for (int dt = 0; dt < 2; dt++){
                f32x4 o = {0.f,0.f,0.f,0.f};
                bf16x8 a0 = *(const bf16x8*)&Vt[h*32 + dt*16 + li_][gt_*8];
                bf16x8 a1 = *(const bf16x8*)&Vt[h*32 + dt*16 + li_][32 + gt_*8];
                o = MFMA16(a0, pb0.v, o);
                o = MFMA16(a1, pb1.v, o);
                ov[ui][dt] = o;
            }
            __builtin_amdgcn_s_setprio(0);
        }
        __syncthreads();   // all Qs reads done
        // P3: attn-out -> Qs
        #pragma unroll
        for (int ui = 0; ui < 3; ui++){
            const int u = w * 3 + ui;
            const int h = u >> 2, qct = u & 3;
            const int tok = qct * 16 + li_;
            #pragma unroll
            for (int dt = 0; dt < 2; dt++){
                int cb = h * 32 + dt * 16 + (gt_ << 2);
                bf16x4 t;
                #pragma unroll
                for (int r = 0; r < 4; r++) t[r] = (__bf16)ov[ui][dt][r];
                *(bf16x4*)&Qs[tok][cb] = t;
            }
        }
        __syncthreads();
        {   // P4: outproj: y = ysl + Wp^T @ out^T + bpj  (pure store)
            const int ct = w & 3, rh = w >> 2;
            const int ql = ct * 16 + li_;
            const int ft = ((b * 32 + 8 * sw_ + qt) * 64 + 8 * hw_ + (ql >> 3)) * 64 + 8 * ww_ + (ql & 7);
            bf16x8 bfr[6];
            #pragma unroll
            for (int kt = 0; kt < 6; kt++) bfr[kt] = *(const bf16x8*)&Qs[ql][kt*32 + gt_*8];
            #pragma unroll
            for (int i = 0; i < 3; i++){
                int rt = rh * 3 + i;
                f32x4 acc = {0.f,0.f,0.f,0.f};
                #pragma unroll
                for (int kt = 0; kt < 6; kt++) acc = MFMA16(afrag(wsw + WP_OFF, 6, kt, rt, lane), bfr[kt], acc);
                int cb = rt * 16 + (gt_ << 2);
                float4 b4 = *(const float4*)&bpj[cb];
                float4 yv = *(const float4*)&ysl[ql][cb];
                float4 res;
                res.x = yv.x + acc[0] + b4.x;
                res.y = yv.y + acc[1] + b4.y;
                res.z = yv.z + acc[2] + b4.z;
                res.w = yv.w + acc[3] + b4.w;
                *(float4*)&yout[ft * 96 + cb] = res;
            }
        }
        __syncthreads();   // before next qt overwrites Qs / ysl
    }
}

// ---------------- MLP (MFMA): d_out = y + W2(gelu(W1 ln(y)+b1))+b2, in place ----------------
// hidden processed in 2 halves of 192 -> LDS 51.2 KB -> up to 3 blocks/CU
__global__ __launch_bounds__(512) void k_mlp(const float* __restrict__ y,
    const float* __restrict__ g2, const float* __restrict__ b2v,
    const __bf16* __restrict__ wsw, const float* __restrict__ b1m,
    const float* __restrict__ b2m, float* __restrict__ outp){
    __shared__ __bf16 yln[64][104];
    __shared__ __bf16 hsm[64][200];
    __shared__ __bf16 ybf[64][96];    // raw y stash for residual
    const int tid = threadIdx.x, lane = tid & 63, w = tid >> 6;
    const int t0 = blockIdx.x * 64;
    {   // LN stage
        int row = tid >> 3, sub = tid & 7;
        const float* yp = y + (t0 + row) * 96 + sub * 12;
        float v[12]; float s = 0.f, ss = 0.f;
        #pragma unroll
        for (int i = 0; i < 3; i++){
            float4 t = ((const float4*)yp)[i];
            v[4*i] = t.x; v[4*i+1] = t.y; v[4*i+2] = t.z; v[4*i+3] = t.w;
            s += t.x + t.y + t.z + t.w;
            ss += t.x*t.x + t.y*t.y + t.z*t.z + t.w*t.w;
        }
        #pragma unroll
        for (int i = 0; i < 3; i++){
            bf16x4 t;
            #pragma unroll
            for (int jj = 0; jj < 4; jj++) t[jj] = (__bf16)v[4*i+jj];
            *(bf16x4*)&ybf[row][sub*12 + 4*i] = t;
        }
        #pragma unroll
        for (int m = 1; m < 8; m <<= 1){ s += __shfl_xor(s, m); ss += __shfl_xor(ss, m); }
        float mu = s * (1.f/96.f), var = ss * (1.f/96.f) - mu*mu, rs = rsqrtf(var + 1e-5f);
        #pragma unroll
        for (int i = 0; i < 3; i++){
            bf16x4 t;
            #pragma unroll
            for (int jj = 0; jj < 4; jj++){
                int c = sub*12 + 4*i + jj;
                t[jj] = (__bf16)((v[4*i+jj] - mu) * rs * g2[c] + b2v[c]);
            }
            *(bf16x4*)&yln[row][sub*12 + 4*i] = t;
        }
    }
    __syncthreads();
    const int ct = w & 3, rh = w >> 2;
    const int tok = ct * 16 + (lane & 15);
    bf16x8 bfrY[3];
    #pragma unroll
    for (int kt = 0; kt < 3; kt++) bfrY[kt] = *(const bf16x8*)&yln[tok][kt*32 + (lane>>4)*8];
    f32x4 oacc[3];
    #pragma unroll
    for (int i = 0; i < 3; i++){ f32x4 z = {0.f,0.f,0.f,0.f}; oacc[i] = z; }

    #pragma unroll
    for (int hh = 0; hh < 2; hh++){
        // GEMM1 half: h^T = W1^T @ yln^T, gelu -> hsm
        #pragma unroll
        for (int i = 0; i < 6; i++){
            int rtl = rh * 6 + i;            // [0,12)
            int rtg = hh * 12 + rtl;
            f32x4 acc = {0.f,0.f,0.f,0.f};
            #pragma unroll
            for (int kt = 0; kt < 3; kt++) acc = MFMA16(afrag(wsw + W1_OFF, 24, kt, rtg, lane), bfrY[kt], acc);
            int cb = rtl * 16 + ((lane >> 4) << 2);
            float4 b4 = *(const float4*)&b1m[hh * 192 + cb];
            bf16x4 t;
            t[0] = (__bf16)gelu_exact(acc[0] + b4.x);
            t[1] = (__bf16)gelu_exact(acc[1] + b4.y);
            t[2] = (__bf16)gelu_exact(acc[2] + b4.z);
            t[3] = (__bf16)gelu_exact(acc[3] + b4.w);
            *(bf16x4*)&hsm[tok][cb] = t;
        }
        __syncthreads();
        // GEMM2 half: accumulate o^T += W2half^T @ h^T
        bf16x8 bfrH[6];
        #pragma unroll
        for (int kt = 0; kt < 6; kt++) bfrH[kt] = *(const bf16x8*)&hsm[tok][kt*32 + (lane>>4)*8];
        #pragma unroll
        for (int i = 0; i < 3; i++){
            int rt = rh * 3 + i;
            #pragma unroll
            for (int kt = 0; kt < 6; kt++)
                oacc[i] = MFMA16(afrag(wsw + W2_OFF, 6, hh * 6 + kt, rt, lane), bfrH[kt], oacc[i]);
        }
        __syncthreads();
    }
    #pragma unroll
    for (int i = 0; i < 3; i++){
        int rt = rh * 3 + i;
        int cb = rt * 16 + ((lane >> 4) << 2);
        float4 b4 = *(const float4*)&b2m[cb];
        bf16x4 yv = *(const bf16x4*)&ybf[tok][cb];
        float4 res;
        res.x = (float)yv[0] + oacc[i][0] + b4.x;
        res.y = (float)yv[1] + oacc[i][1] + b4.y;
        res.z = (float)yv[2] + oacc[i][2] + b4.z;
        res.w = (float)yv[3] + oacc[i][3] + b4.w;
        *(float4*)&outp[(t0 + tok) * 96 + cb] = res;
    }
}

extern "C" void kernel_launch(void* const* d_in, const int* in_sizes, int n_in,
                              void* d_out, int out_size, void* d_ws, size_t ws_size,
                              hipStream_t stream){
    const float* x    = (const float*)d_in[0];
    const float* xd   = (const float*)d_in[1];
    const float* g1   = (const float*)d_in[2];
    const float* b1v  = (const float*)d_in[3];
    const float* Wkv  = (const float*)d_in[4];
    const float* bkv  = (const float*)d_in[5];
    const float* Wq   = (const float*)d_in[6];
    const float* bq   = (const float*)d_in[7];
    const float* Wp   = (const float*)d_in[8];
    const float* bpj  = (const float*)d_in[9];
    const float* btab = (const float*)d_in[10];
    const float* eg   = (const float*)d_in[11];
    const float* eb   = (const float*)d_in[12];
    const float* dw   = (const float*)d_in[13];
    const float* db   = (const float*)d_in[14];
    const float* g2   = (const float*)d_in[15];
    const float* b2v  = (const float*)d_in[16];
    const float* W1   = (const float*)d_in[17];
    const float* b1m  = (const float*)d_in[18];
    const float* W2   = (const float*)d_in[19];
    const float* b2m  = (const float*)d_in[20];
    (void)in_sizes; (void)n_in; (void)out_size; (void)ws_size;

    float*   out  = (float*)d_out;
    float*   bias = (float*)d_ws;
    __bf16*  wsw  = (__bf16*)((char*)d_ws + BIAS_BYTES);

    k_prep<<<2064, 256, 0, stream>>>(btab, Wkv, Wq, Wp, dw, W1, W2, bias, wsw);
    k_attn<<<512, 512, 0, stream>>>(x, xd, g1, b1v, eg, eb, bkv, bq, bpj, db, wsw, bias, out);
    k_mlp <<<4096, 512, 0, stream>>>(out, g2, b2v, wsw, b1m, b2m, out);
}

// Round 7
// 392.489 us; speedup vs baseline: 1.0486x; 1.0486x over previous
//
#include <hip/hip_runtime.h>
#include <math.h>

#define ATT_SCALE 0.17677669529663687f  // 32^-0.5

typedef __bf16 bf16x8 __attribute__((ext_vector_type(8)));
typedef __bf16 bf16x4 __attribute__((ext_vector_type(4)));
typedef float  f32x4  __attribute__((ext_vector_type(4)));

#define MFMA16(a,b,c) __builtin_amdgcn_mfma_f32_16x16x32_bf16(a,b,c,0,0,0)

// ws layout: [0,786432) f32 expanded bias; then bf16 swizzled weights
#define BIAS_BYTES 786432
#define WKV_OFF 0        // 192x384  kt6  NRT24
#define WQ_OFF  73728    // 96x192   kt3  NRT12 (pre-scaled)
#define WP_OFF  92160    // 192x96   kt6  NRT6
#define WD_OFF  110592   // 192x768  kt6  NRT48
#define W1_OFF  258048   // 96x384   kt3  NRT24
#define W2_OFF  294912   // 384x96   kt12 NRT6
#define NSWZ    331776

static __device__ __forceinline__ float gelu_exact(float v){
    return 0.5f * v * (1.0f + erff(v * 0.70710678118654752f));
}

static __device__ __forceinline__ bf16x8 afrag(const __bf16* w, int NRT, int kt, int rt, int lane){
    return ((const bf16x8*)w)[(kt*NRT + rt)*64 + lane];
}

// ---------------- prep: bias expand + weight bf16 swizzle ----------------
__global__ __launch_bounds__(256) void k_prep(const float* __restrict__ table,
    const float* __restrict__ Wkv, const float* __restrict__ Wq,
    const float* __restrict__ Wp,  const float* __restrict__ Wd,
    const float* __restrict__ W1,  const float* __restrict__ W2,
    float* __restrict__ bias, __bf16* __restrict__ wsw){
    int id = blockIdx.x * 256 + threadIdx.x;
    if (id < 196608){
        int k  = id & 63;
        int qg = (id >> 6) & 511;
        int h  = id >> 15;
        int qi = qg >> 6, qj = (qg >> 3) & 7, qk = qg & 7;
        int ki = k >> 4,  kj = (k >> 2) & 3,  kk = k & 3;
        int r0 = (qi >> 1) - ki + 3;
        int r1 = (qj >> 1) - kj + 3;
        int r2 = (qk >> 1) - kk + 3;
        bias[id] = table[((r0 * 7 + r1) * 7 + r2) * 6 + h];
        return;
    }
    id -= 196608;
    if (id >= NSWZ) return;
    const float* W; int N, NRT, off; float sc = 1.f;
    if      (id < WQ_OFF){ W = Wkv; N = 384; NRT = 24; off = WKV_OFF; }
    else if (id < WP_OFF){ W = Wq;  N = 192; NRT = 12; off = WQ_OFF; sc = ATT_SCALE; }
    else if (id < WD_OFF){ W = Wp;  N = 96;  NRT = 6;  off = WP_OFF; }
    else if (id < W1_OFF){ W = Wd;  N = 768; NRT = 48; off = WD_OFF; }
    else if (id < W2_OFF){ W = W1;  N = 384; NRT = 24; off = W1_OFF; }
    else                 { W = W2;  N = 96;  NRT = 6;  off = W2_OFF; }
    int lid  = id - off;
    int j    = lid & 7, lane = (lid >> 3) & 63, tile = lid >> 9;
    int rt   = tile % NRT, kt = tile / NRT;
    int n    = rt * 16 + (lane & 15);
    int k    = kt * 32 + (lane >> 4) * 8 + j;
    wsw[id + 0] = (__bf16)(W[k * N + n] * sc);
}

// ---------------- deconv path (MFMA): d_out = sc (full overwrite) ----------------
__global__ __launch_bounds__(512) void k_deconv(const float* __restrict__ x,
    const float* __restrict__ eg, const float* __restrict__ eb,
    const __bf16* __restrict__ wsw, const float* __restrict__ db,
    float* __restrict__ out){
    __shared__ __bf16 xe[64][200];
    const int tid = threadIdx.x, lane = tid & 63, w = tid >> 6;
    const int ci0 = blockIdx.x * 64;
    {   // LN stage -> bf16
        int row = tid >> 3, sub = tid & 7;
        const float* xp = x + (ci0 + row) * 192 + sub * 24;
        float v[24]; float s = 0.f, ss = 0.f;
        #pragma unroll
        for (int i = 0; i < 6; i++){
            float4 t = ((const float4*)xp)[i];
            v[4*i] = t.x; v[4*i+1] = t.y; v[4*i+2] = t.z; v[4*i+3] = t.w;
            s += t.x + t.y + t.z + t.w;
            ss += t.x*t.x + t.y*t.y + t.z*t.z + t.w*t.w;
        }
        #pragma unroll
        for (int m = 1; m < 8; m <<= 1){ s += __shfl_xor(s, m); ss += __shfl_xor(ss, m); }
        float mu = s * (1.f/192.f), var = ss * (1.f/192.f) - mu*mu, rs = rsqrtf(var + 1e-5f);
        #pragma unroll
        for (int i = 0; i < 3; i++){
            bf16x8 t;
            #pragma unroll
            for (int jj = 0; jj < 8; jj++){
                int c = sub*24 + 8*i + jj;
                t[jj] = (__bf16)((v[8*i+jj] - mu) * rs * eg[c] + eb[c]);
            }
            *(bf16x8*)&xe[row][sub*24 + 8*i] = t;
        }
    }
    __syncthreads();
    const int ct = w & 3, rh = w >> 2;
    const int tok = ct * 16 + (lane & 15);
    const int ci  = ci0 + tok;
    const int bb  = ci >> 14, rem = ci & 16383;
    const int sC  = rem >> 10, hC = (rem >> 5) & 31, wC = rem & 31;
    const int ftb = ((bb * 32 + 2 * sC) * 64 + 2 * hC) * 64 + 2 * wC;
    bf16x8 bfr[6];
    #pragma unroll
    for (int kt = 0; kt < 6; kt++) bfr[kt] = *(const bf16x8*)&xe[tok][kt*32 + (lane>>4)*8];
    for (int i = 0; i < 24; i++){
        int rt = rh * 24 + i;
        f32x4 acc = {0.f,0.f,0.f,0.f};
        #pragma unroll
        for (int kt = 0; kt < 6; kt++) acc = MFMA16(afrag(wsw + WD_OFF, 48, kt, rt, lane), bfr[kt], acc);
        int nb = rt * 16 + ((lane >> 4) << 2);
        int o = nb >> 3, ij0 = nb & 7;
        float bo = db[o];
        #pragma unroll
        for (int r = 0; r < 4; r++){
            int ijk = ij0 + r;
            int ft = ftb + (ijk >> 2) * 4096 + ((ijk >> 1) & 1) * 64 + (ijk & 1);
            out[ft * 96 + o] = acc[r] + bo;
        }
    }
}

// ---------------- fused windowed cross-attention (MFMA): d_out += attn ----------------
// proven r4 structure: LDS 74.5 KB, ds_bpermute P redistribution, setprio on MFMA clusters
__global__ __launch_bounds__(512) void k_attn(const float* __restrict__ x,
    const float* __restrict__ xd, const float* __restrict__ g1, const float* __restrict__ b1v,
    const float* __restrict__ bkv, const float* __restrict__ bq, const float* __restrict__ bpj,
    const __bf16* __restrict__ wsw, const float* __restrict__ bias, float* __restrict__ yout){
    __shared__ __bf16 Qs[64][196];   // xln -> Q -> attn-out (aliased phases)
    __shared__ __bf16 Ks[64][196];
    __shared__ __bf16 Vt[192][68];   // V transposed [d][kv]
    const int tid = threadIdx.x, lane = tid & 63, w = tid >> 6;
    const int win = blockIdx.x, b = win >> 8, wrem = win & 255;
    const int sw_ = wrem >> 6, hw_ = (wrem >> 3) & 7, ww_ = wrem & 7;

    {   // LN stage of coarse x window -> Qs (as xln)
        int row = tid >> 3, sub = tid & 7;
        int si = row >> 4, hi = (row >> 2) & 3, wi = row & 3;
        int ci = ((b * 16 + 4 * sw_ + si) * 32 + 4 * hw_ + hi) * 32 + 4 * ww_ + wi;
        const float* xp = x + ci * 192 + sub * 24;
        float v[24]; float s = 0.f, ss = 0.f;
        #pragma unroll
        for (int i = 0; i < 6; i++){
            float4 t = ((const float4*)xp)[i];
            v[4*i] = t.x; v[4*i+1] = t.y; v[4*i+2] = t.z; v[4*i+3] = t.w;
            s += t.x + t.y + t.z + t.w;
            ss += t.x*t.x + t.y*t.y + t.z*t.z + t.w*t.w;
        }
        #pragma unroll
        for (int m = 1; m < 8; m <<= 1){ s += __shfl_xor(s, m); ss += __shfl_xor(ss, m); }
        float mu = s * (1.f/192.f), var = ss * (1.f/192.f) - mu*mu, rs = rsqrtf(var + 1e-5f);
        #pragma unroll
        for (int i = 0; i < 3; i++){
            bf16x8 t;
            #pragma unroll
            for (int jj = 0; jj < 8; jj++){
                int c = sub*24 + 8*i + jj;
                t[jj] = (__bf16)((v[8*i+jj] - mu) * rs * g1[c] + b1v[c]);
            }
            *(bf16x8*)&Qs[row][sub*24 + 8*i] = t;
        }
    }
    __syncthreads();
    {   // KVproj: KV^T = Wkv^T @ xln^T ; waves 0-3 -> K rows, 4-7 -> V^T
        const int ct = w & 3, rh = w >> 2;
        const int tok = ct * 16 + (lane & 15);
        bf16x8 bfr[6];
        #pragma unroll
        for (int kt = 0; kt < 6; kt++) bfr[kt] = *(const bf16x8*)&Qs[tok][kt*32 + (lane>>4)*8];
        #pragma unroll
        for (int i = 0; i < 12; i++){
            int rt = rh * 12 + i;
            f32x4 acc = {0.f,0.f,0.f,0.f};
            #pragma unroll
            for (int kt = 0; kt < 6; kt++) acc = MFMA16(afrag(wsw + WKV_OFF, 24, kt, rt, lane), bfr[kt], acc);
            int cb = rt * 16 + ((lane >> 4) << 2);
            float4 b4 = *(const float4*)&bkv[cb];
            acc[0] += b4.x; acc[1] += b4.y; acc[2] += b4.z; acc[3] += b4.w;
            if (cb < 192){
                bf16x4 t;
                #pragma unroll
                for (int r = 0; r < 4; r++) t[r] = (__bf16)acc[r];
                *(bf16x4*)&Ks[tok][cb] = t;
            } else {
                #pragma unroll
                for (int r = 0; r < 4; r++) Vt[cb - 192 + r][tok] = (__bf16)acc[r];
            }
        }
    }
    __syncthreads();

    const int li_ = lane & 15, gt_ = lane >> 4, rsel = lane >> 5;

    for (int qt = 0; qt < 8; qt++){
        {   // Qproj: Q^T = Wq^T(scaled) @ xd^T ; B-frags straight from global f32
            const int ct = w & 3, rh = w >> 2;
            const int ql = ct * 16 + (lane & 15);
            const int ft = ((b * 32 + 8 * sw_ + qt) * 64 + 8 * hw_ + (ql >> 3)) * 64 + 8 * ww_ + (ql & 7);
            bf16x8 bfr[3];
            #pragma unroll
            for (int kt = 0; kt < 3; kt++){
                const float* xp = xd + ft * 96 + kt * 32 + (lane >> 4) * 8;
                float4 t0 = *(const float4*)xp;
                float4 t1 = *(const float4*)(xp + 4);
                bf16x8 t;
                t[0]=(__bf16)t0.x; t[1]=(__bf16)t0.y; t[2]=(__bf16)t0.z; t[3]=(__bf16)t0.w;
                t[4]=(__bf16)t1.x; t[5]=(__bf16)t1.y; t[6]=(__bf16)t1.z; t[7]=(__bf16)t1.w;
                bfr[kt] = t;
            }
            #pragma unroll
            for (int i = 0; i < 6; i++){
                int rt = rh * 6 + i;
                f32x4 acc = {0.f,0.f,0.f,0.f};
                #pragma unroll
                for (int kt = 0; kt < 3; kt++) acc = MFMA16(afrag(wsw + WQ_OFF, 12, kt, rt, lane), bfr[kt], acc);
                int cb = rt * 16 + ((lane >> 4) << 2);
                float4 b4 = *(const float4*)&bq[cb];
                bf16x4 t;
                t[0] = (__bf16)(acc[0] + b4.x * ATT_SCALE);
                t[1] = (__bf16)(acc[1] + b4.y * ATT_SCALE);
                t[2] = (__bf16)(acc[2] + b4.z * ATT_SCALE);
                t[3] = (__bf16)(acc[3] + b4.w * ATT_SCALE);
                *(bf16x4*)&Qs[ql][cb] = t;
            }
        }
        __syncthreads();
        // scores + softmax + in-register P redistribution + PV
        f32x4 ov[3][2];
        #pragma unroll
        for (int ui = 0; ui < 3; ui++){
            const int u = w * 3 + ui;
            const int h = u >> 2, qct = u & 3;
            f32x4 sc[4];
            __builtin_amdgcn_s_setprio(1);
            #pragma unroll
            for (int rt = 0; rt < 4; rt++){
                bf16x8 a  = *(const bf16x8*)&Ks[rt*16 + li_][h*32 + gt_*8];
                bf16x8 bq8 = *(const bf16x8*)&Qs[qct*16 + li_][h*32 + gt_*8];
                f32x4 z = {0.f,0.f,0.f,0.f};
                sc[rt] = MFMA16(a, bq8, z);
            }
            __builtin_amdgcn_s_setprio(0);
            const int qg = qt * 64 + qct * 16 + li_;
            const float* bp = bias + (h * 512 + qg) * 64 + (gt_ << 2);
            #pragma unroll
            for (int rt = 0; rt < 4; rt++){
                float4 b4 = *(const float4*)(bp + rt * 16);
                sc[rt][0] += b4.x; sc[rt][1] += b4.y; sc[rt][2] += b4.z; sc[rt][3] += b4.w;
            }
            float m = sc[0][0];
            #pragma unroll
            for (int rt = 0; rt < 4; rt++)
                #pragma unroll
                for (int r = 0; r < 4; r++) m = fmaxf(m, sc[rt][r]);
            m = fmaxf(m, __shfl_xor(m, 16));
            m = fmaxf(m, __shfl_xor(m, 32));
            float sum = 0.f;
            #pragma unroll
            for (int rt = 0; rt < 4; rt++)
                #pragma unroll
                for (int r = 0; r < 4; r++){ float e = __expf(sc[rt][r] - m); sc[rt][r] = e; sum += e; }
            sum += __shfl_xor(sum, 16);
            sum += __shfl_xor(sum, 32);
            float inv = 1.f / sum;
            // pack normalized P into bf16 pair words: pwv[rt][h2] covers kv = rt*16+gt*4+2*h2+{0,1}
            unsigned pwv[4][2];
            #pragma unroll
            for (int rt = 0; rt < 4; rt++){
                union { __bf16 hh[2]; unsigned u; } c0, c1;
                c0.hh[0] = (__bf16)(sc[rt][0] * inv); c0.hh[1] = (__bf16)(sc[rt][1] * inv);
                c1.hh[0] = (__bf16)(sc[rt][2] * inv); c1.hh[1] = (__bf16)(sc[rt][3] * inv);
                pwv[rt][0] = c0.u; pwv[rt][1] = c1.u;
            }
            // redistribute C-frag -> B-frag layout: word t of kt comes from lane gs*16+li,
            // tile rt_s = 2kt + rsel, pair h2 = t&1, gs = 2*(gt&1) + (t>>1)
            unsigned bfw[2][4];
            #pragma unroll
            for (int kt = 0; kt < 2; kt++){
                #pragma unroll
                for (int t = 0; t < 4; t++){
                    int gs   = ((gt_ & 1) << 1) + (t >> 1);
                    int addr = (((gs << 4) + li_) << 2);
                    int w0 = __builtin_amdgcn_ds_bpermute(addr, (int)pwv[2*kt + 0][t & 1]);
                    int w1 = __builtin_amdgcn_ds_bpermute(addr, (int)pwv[2*kt + 1][t & 1]);
                    bfw[kt][t] = rsel ? (unsigned)w1 : (unsigned)w0;
                }
            }
            union { unsigned u[4]; bf16x8 v; } pb0, pb1;
            #pragma unroll
            for (int t = 0; t < 4; t++){ pb0.u[t] = bfw[0][t]; pb1.u[t] = bfw[1][t]; }
            __builtin_amdgcn_s_setprio(1);
            #pragma unroll
            for (int dt = 0; dt < 2; dt++){
                f32x4 o = {0.f,0.f,0.f,0.f};
                bf16x8 a0 = *(const bf16x8*)&Vt[h*32 + dt*16 + li_][gt_*8];
                bf16x8 a1 = *(const bf16x8*)&Vt[h*32 + dt*16 + li_][32 + gt_*8];
                o = MFMA16(a0, pb0.v, o);
                o = MFMA16(a1, pb1.v, o);
                ov[ui][dt] = o;
            }
            __builtin_amdgcn_s_setprio(0);
        }
        __syncthreads();   // all Qs reads done
        #pragma unroll
        for (int ui = 0; ui < 3; ui++){
            const int u = w * 3 + ui;
            const int h = u >> 2, qct = u & 3;
            const int tok = qct * 16 + li_;
            #pragma unroll
            for (int dt = 0; dt < 2; dt++){
                int cb = h * 32 + dt * 16 + (gt_ << 2);
                bf16x4 t;
                #pragma unroll
                for (int r = 0; r < 4; r++) t[r] = (__bf16)ov[ui][dt][r];
                *(bf16x4*)&Qs[tok][cb] = t;
            }
        }
        __syncthreads();
        {   // outproj: Y^T = Wp^T @ out^T ; += into d_out (y = sc + attn)
            const int ct = w & 3, rh = w >> 2;
            const int ql = ct * 16 + (lane & 15);
            const int ft = ((b * 32 + 8 * sw_ + qt) * 64 + 8 * hw_ + (ql >> 3)) * 64 + 8 * ww_ + (ql & 7);
            bf16x8 bfr[6];
            #pragma unroll
            for (int kt = 0; kt < 6; kt++) bfr[kt] = *(const bf16x8*)&Qs[ql][kt*32 + (lane>>4)*8];
            #pragma unroll
            for (int i = 0; i < 3; i++){
                int rt = rh * 3 + i;
                f32x4 acc = {0.f,0.f,0.f,0.f};
                #pragma unroll
                for (int kt = 0; kt < 6; kt++) acc = MFMA16(afrag(wsw + WP_OFF, 6, kt, rt, lane), bfr[kt], acc);
                int cb = rt * 16 + ((lane >> 4) << 2);
                float4 b4 = *(const float4*)&bpj[cb];
                float4 old = *(const float4*)&yout[ft * 96 + cb];
                float4 res;
                res.x = old.x + acc[0] + b4.x;
                res.y = old.y + acc[1] + b4.y;
                res.z = old.z + acc[2] + b4.z;
                res.w = old.w + acc[3] + b4.w;
                *(float4*)&yout[ft * 96 + cb] = res;
            }
        }
        __syncthreads();   // before next qt overwrites Qs
    }
}

// ---------------- MLP (MFMA): d_out = y + W2(gelu(W1 ln(y)+b1))+b2, in place ----------------
// hidden processed in 2 halves of 192 -> LDS 51.2 KB (proven in round 5)
__global__ __launch_bounds__(512) void k_mlp(const float* __restrict__ y,
    const float* __restrict__ g2, const float* __restrict__ b2v,
    const __bf16* __restrict__ wsw, const float* __restrict__ b1m,
    const float* __restrict__ b2m, float* __restrict__ outp){
    __shared__ __bf16 yln[64][104];
    __shared__ __bf16 hsm[64][200];
    __shared__ __bf16 ybf[64][96];    // raw y stash for residual
    const int tid = threadIdx.x, lane = tid & 63, w = tid >> 6;
    const int t0 = blockIdx.x * 64;
    {   // LN stage
        int row = tid >> 3, sub = tid & 7;
        const float* yp = y + (t0 + row) * 96 + sub * 12;
        float v[12]; float s = 0.f, ss = 0.f;
        #pragma unroll
        for (int i = 0; i < 3; i++){
            float4 t = ((const float4*)yp)[i];
            v[4*i] = t.x; v[4*i+1] = t.y; v[4*i+2] = t.z; v[4*i+3] = t.w;
            s += t.x + t.y + t.z + t.w;
            ss += t.x*t.x + t.y*t.y + t.z*t.z + t.w*t.w;
        }
        #pragma unroll
        for (int i = 0; i < 3; i++){
            bf16x4 t;
            #pragma unroll
            for (int jj = 0; jj < 4; jj++) t[jj] = (__bf16)v[4*i+jj];
            *(bf16x4*)&ybf[row][sub*12 + 4*i] = t;
        }
        #pragma unroll
        for (int m = 1; m < 8; m <<= 1){ s += __shfl_xor(s, m); ss += __shfl_xor(ss, m); }
        float mu = s * (1.f/96.f), var = ss * (1.f/96.f) - mu*mu, rs = rsqrtf(var + 1e-5f);
        #pragma unroll
        for (int i = 0; i < 3; i++){
            bf16x4 t;
            #pragma unroll
            for (int jj = 0; jj < 4; jj++){
                int c = sub*12 + 4*i + jj;
                t[jj] = (__bf16)((v[4*i+jj] - mu) * rs * g2[c] + b2v[c]);
            }
            *(bf16x4*)&yln[row][sub*12 + 4*i] = t;
        }
    }
    __syncthreads();
    const int ct = w & 3, rh = w >> 2;
    const int tok = ct * 16 + (lane & 15);
    bf16x8 bfrY[3];
    #pragma unroll
    for (int kt = 0; kt < 3; kt++) bfrY[kt] = *(const bf16x8*)&yln[tok][kt*32 + (lane>>4)*8];
    f32x4 oacc[3];
    #pragma unroll
    for (int i = 0; i < 3; i++){ f32x4 z = {0.f,0.f,0.f,0.f}; oacc[i] = z; }

    #pragma unroll
    for (int hh = 0; hh < 2; hh++){
        // GEMM1 half: h^T = W1^T @ yln^T, gelu -> hsm
        #pragma unroll
        for (int i = 0; i < 6; i++){
            int rtl = rh * 6 + i;            // [0,12)
            int rtg = hh * 12 + rtl;
            f32x4 acc = {0.f,0.f,0.f,0.f};
            #pragma unroll
            for (int kt = 0; kt < 3; kt++) acc = MFMA16(afrag(wsw + W1_OFF, 24, kt, rtg, lane), bfrY[kt], acc);
            int cb = rtl * 16 + ((lane >> 4) << 2);
            float4 b4 = *(const float4*)&b1m[hh * 192 + cb];
            bf16x4 t;
            t[0] = (__bf16)gelu_exact(acc[0] + b4.x);
            t[1] = (__bf16)gelu_exact(acc[1] + b4.y);
            t[2] = (__bf16)gelu_exact(acc[2] + b4.z);
            t[3] = (__bf16)gelu_exact(acc[3] + b4.w);
            *(bf16x4*)&hsm[tok][cb] = t;
        }
        __syncthreads();
        // GEMM2 half: accumulate o^T += W2half^T @ h^T
        bf16x8 bfrH[6];
        #pragma unroll
        for (int kt = 0; kt < 6; kt++) bfrH[kt] = *(const bf16x8*)&hsm[tok][kt*32 + (lane>>4)*8];
        #pragma unroll
        for (int i = 0; i < 3; i++){
            int rt = rh * 3 + i;
            #pragma unroll
            for (int kt = 0; kt < 6; kt++)
                oacc[i] = MFMA16(afrag(wsw + W2_OFF, 6, hh * 6 + kt, rt, lane), bfrH[kt], oacc[i]);
        }
        __syncthreads();
    }
    #pragma unroll
    for (int i = 0; i < 3; i++){
        int rt = rh * 3 + i;
        int cb = rt * 16 + ((lane >> 4) << 2);
        float4 b4 = *(const float4*)&b2m[cb];
        bf16x4 yv = *(const bf16x4*)&ybf[tok][cb];
        float4 res;
        res.x = (float)yv[0] + oacc[i][0] + b4.x;
        res.y = (float)yv[1] + oacc[i][1] + b4.y;
        res.z = (float)yv[2] + oacc[i][2] + b4.z;
        res.w = (float)yv[3] + oacc[i][3] + b4.w;
        *(float4*)&outp[(t0 + tok) * 96 + cb] = res;
    }
}

extern "C" void kernel_launch(void* const* d_in, const int* in_sizes, int n_in,
                              void* d_out, int out_size, void* d_ws, size_t ws_size,
                              hipStream_t stream){
    const float* x    = (const float*)d_in[0];
    const float* xd   = (const float*)d_in[1];
    const float* g1   = (const float*)d_in[2];
    const float* b1v  = (const float*)d_in[3];
    const float* Wkv  = (const float*)d_in[4];
    const float* bkv  = (const float*)d_in[5];
    const float* Wq   = (const float*)d_in[6];
    const float* bq   = (const float*)d_in[7];
    const float* Wp   = (const float*)d_in[8];
    const float* bpj  = (const float*)d_in[9];
    const float* btab = (const float*)d_in[10];
    const float* eg   = (const float*)d_in[11];
    const float* eb   = (const float*)d_in[12];
    const float* dw   = (const float*)d_in[13];
    const float* db   = (const float*)d_in[14];
    const float* g2   = (const float*)d_in[15];
    const float* b2v  = (const float*)d_in[16];
    const float* W1   = (const float*)d_in[17];
    const float* b1m  = (const float*)d_in[18];
    const float* W2   = (const float*)d_in[19];
    const float* b2m  = (const float*)d_in[20];
    (void)in_sizes; (void)n_in; (void)out_size; (void)ws_size;

    float*   out  = (float*)d_out;
    float*   bias = (float*)d_ws;
    __bf16*  wsw  = (__bf16*)((char*)d_ws + BIAS_BYTES);

    k_prep  <<<2064, 256, 0, stream>>>(btab, Wkv, Wq, Wp, dw, W1, W2, bias, wsw);
    k_deconv<<<512, 512, 0, stream>>>(x, eg, eb, wsw, db, out);
    k_attn  <<<512, 512, 0, stream>>>(x, xd, g1, b1v, bkv, bq, bpj, wsw, bias, out);
    k_mlp   <<<4096, 512, 0, stream>>>(out, g2, b2v, wsw, b1m, b2m, out);
}

// Round 8
// 328.438 us; speedup vs baseline: 1.2531x; 1.1950x over previous
//
#include <hip/hip_runtime.h>
#include <math.h>

#define ATT_SCALE 0.17677669529663687f  // 32^-0.5

typedef __bf16 bf16x8 __attribute__((ext_vector_type(8)));
typedef __bf16 bf16x4 __attribute__((ext_vector_type(4)));
typedef float  f32x4  __attribute__((ext_vector_type(4)));

#define MFMA16(a,b,c) __builtin_amdgcn_mfma_f32_16x16x32_bf16(a,b,c,0,0,0)

// ws layout: [0,786432) f32 expanded bias; then bf16 swizzled weights
#define BIAS_BYTES 786432
#define WKV_OFF 0        // 192x384  kt6  NRT24
#define WQ_OFF  73728    // 96x192   kt3  NRT12 (pre-scaled)
#define WP_OFF  92160    // 192x96   kt6  NRT6
#define WD_OFF  110592   // deconv: [ii2][kt6][rt24][lane][8], rows m = jk*96+o
#define W1_OFF  258048   // 96x384   kt3  NRT24
#define W2_OFF  294912   // 384x96   kt12 NRT6
#define NSWZ    331776

static __device__ __forceinline__ float gelu_exact(float v){
    return 0.5f * v * (1.0f + erff(v * 0.70710678118654752f));
}

static __device__ __forceinline__ bf16x8 afrag(const __bf16* w, int NRT, int kt, int rt, int lane){
    return ((const bf16x8*)w)[(kt*NRT + rt)*64 + lane];
}

// ---------------- prep: bias expand + weight bf16 swizzle ----------------
__global__ __launch_bounds__(256) void k_prep(const float* __restrict__ table,
    const float* __restrict__ Wkv, const float* __restrict__ Wq,
    const float* __restrict__ Wp,  const float* __restrict__ Wd,
    const float* __restrict__ W1,  const float* __restrict__ W2,
    float* __restrict__ bias, __bf16* __restrict__ wsw){
    int id = blockIdx.x * 256 + threadIdx.x;
    if (id < 196608){
        int k  = id & 63;
        int qg = (id >> 6) & 511;
        int h  = id >> 15;
        int qi = qg >> 6, qj = (qg >> 3) & 7, qk = qg & 7;
        int ki = k >> 4,  kj = (k >> 2) & 3,  kk = k & 3;
        int r0 = (qi >> 1) - ki + 3;
        int r1 = (qj >> 1) - kj + 3;
        int r2 = (qk >> 1) - kk + 3;
        bias[id] = table[((r0 * 7 + r1) * 7 + r2) * 6 + h];
        return;
    }
    id -= 196608;
    if (id >= NSWZ) return;
    if (id >= WD_OFF && id < W1_OFF){
        // deconv weights (r5-proven layout): rows m = jk*96+o, split by ii
        int lid  = id - WD_OFF;                    // [0, 147456)
        int j    = lid & 7, lane = (lid >> 3) & 63, tile = lid >> 9;  // tile in [0,288)
        int rt   = tile % 24;
        int kt2  = tile / 24;                      // ii*6 + kt
        int ii   = kt2 / 6, kt = kt2 % 6;
        int n    = rt * 16 + (lane & 15);          // m-index
        int o    = n % 96, jk = n / 96;
        int kdim = kt * 32 + (lane >> 4) * 8 + j;
        wsw[id] = (__bf16)(Wd[(kdim * 96 + o) * 8 + ii * 4 + jk]);
        return;
    }
    const float* W; int N, NRT, off; float sc = 1.f;
    if      (id < WQ_OFF){ W = Wkv; N = 384; NRT = 24; off = WKV_OFF; }
    else if (id < WP_OFF){ W = Wq;  N = 192; NRT = 12; off = WQ_OFF; sc = ATT_SCALE; }
    else if (id < WD_OFF){ W = Wp;  N = 96;  NRT = 6;  off = WP_OFF; }
    else if (id < W2_OFF){ W = W1;  N = 384; NRT = 24; off = W1_OFF; }
    else                 { W = W2;  N = 96;  NRT = 6;  off = W2_OFF; }
    int lid  = id - off;
    int j    = lid & 7, lane = (lid >> 3) & 63, tile = lid >> 9;
    int rt   = tile % NRT, kt = tile / NRT;
    int n    = rt * 16 + (lane & 15);
    int k    = kt * 32 + (lane >> 4) * 8 + j;
    wsw[id + 0] = (__bf16)(W[k * N + n] * sc);
}

// ---------------- deconv path (MFMA): d_out = sc (full overwrite), float4 stores ----------------
__global__ __launch_bounds__(512) void k_deconv(const float* __restrict__ x,
    const float* __restrict__ eg, const float* __restrict__ eb,
    const __bf16* __restrict__ wsw, const float* __restrict__ db,
    float* __restrict__ out){
    __shared__ __bf16 xe[64][200];
    const int tid = threadIdx.x, lane = tid & 63, w = tid >> 6;
    const int ci0 = blockIdx.x * 64;
    {   // LN stage -> bf16
        int row = tid >> 3, sub = tid & 7;
        const float* xp = x + (ci0 + row) * 192 + sub * 24;
        float v[24]; float s = 0.f, ss = 0.f;
        #pragma unroll
        for (int i = 0; i < 6; i++){
            float4 t = ((const float4*)xp)[i];
            v[4*i] = t.x; v[4*i+1] = t.y; v[4*i+2] = t.z; v[4*i+3] = t.w;
            s += t.x + t.y + t.z + t.w;
            ss += t.x*t.x + t.y*t.y + t.z*t.z + t.w*t.w;
        }
        #pragma unroll
        for (int m = 1; m < 8; m <<= 1){ s += __shfl_xor(s, m); ss += __shfl_xor(ss, m); }
        float mu = s * (1.f/192.f), var = ss * (1.f/192.f) - mu*mu, rs = rsqrtf(var + 1e-5f);
        #pragma unroll
        for (int i = 0; i < 3; i++){
            bf16x8 t;
            #pragma unroll
            for (int jj = 0; jj < 8; jj++){
                int c = sub*24 + 8*i + jj;
                t[jj] = (__bf16)((v[8*i+jj] - mu) * rs * eg[c] + eb[c]);
            }
            *(bf16x8*)&xe[row][sub*24 + 8*i] = t;
        }
    }
    __syncthreads();
    const int li = lane & 15, gt = lane >> 4;
    const int ct = w & 3, ii = w >> 2;          // 4 token-tiles x 2 deconv-i halves
    const int tok = ct * 16 + li;
    const int ci  = ci0 + tok;
    const int bb  = ci >> 14, rem = ci & 16383;
    const int sC  = rem >> 10, hC = (rem >> 5) & 31, wC = rem & 31;
    const int ftb = ((bb * 32 + 2 * sC) * 64 + 2 * hC) * 64 + 2 * wC + ii * 4096;
    bf16x8 bfr[6];
    #pragma unroll
    for (int kt = 0; kt < 6; kt++) bfr[kt] = *(const bf16x8*)&xe[tok][kt*32 + gt*8];
    const __bf16* wd = wsw + WD_OFF + ii * 73728;
    for (int rt = 0; rt < 24; rt++){
        f32x4 acc = {0.f,0.f,0.f,0.f};
        #pragma unroll
        for (int kt = 0; kt < 6; kt++) acc = MFMA16(afrag(wd, 24, kt, rt, lane), bfr[kt], acc);
        int m  = rt * 16 + (gt << 2);
        int jk = m / 96, o = m - jk * 96;
        int ft = ftb + (jk >> 1) * 64 + (jk & 1);
        float4 d4 = *(const float4*)&db[o];
        float4 res;
        res.x = acc[0] + d4.x; res.y = acc[1] + d4.y;
        res.z = acc[2] + d4.z; res.w = acc[3] + d4.w;
        *(float4*)&out[ft * 96 + o] = res;
    }
}

// ---------------- fused windowed cross-attention (MFMA): d_out += attn ----------------
// 2 barriers per q-tile: B {scores+softmax+PV -> Os} | A {outproj(qt) + Qproj(qt+1)}
__global__ __launch_bounds__(512) void k_attn(const float* __restrict__ x,
    const float* __restrict__ xd, const float* __restrict__ g1, const float* __restrict__ b1v,
    const float* __restrict__ bkv, const float* __restrict__ bq, const float* __restrict__ bpj,
    const __bf16* __restrict__ wsw, const float* __restrict__ bias, float* __restrict__ yout){
    __shared__ __bf16 Qs[64][196];   // xln -> Q
    __shared__ __bf16 Os[64][196];   // attn-out
    __shared__ __bf16 Ks[64][196];
    __shared__ __bf16 Vt[192][68];   // V transposed [d][kv]
    const int tid = threadIdx.x, lane = tid & 63, w = tid >> 6;
    const int win = blockIdx.x, b = win >> 8, wrem = win & 255;
    const int sw_ = wrem >> 6, hw_ = (wrem >> 3) & 7, ww_ = wrem & 7;

    {   // LN stage of coarse x window -> Qs (as xln)
        int row = tid >> 3, sub = tid & 7;
        int si = row >> 4, hi = (row >> 2) & 3, wi = row & 3;
        int ci = ((b * 16 + 4 * sw_ + si) * 32 + 4 * hw_ + hi) * 32 + 4 * ww_ + wi;
        const float* xp = x + ci * 192 + sub * 24;
        float v[24]; float s = 0.f, ss = 0.f;
        #pragma unroll
        for (int i = 0; i < 6; i++){
            float4 t = ((const float4*)xp)[i];
            v[4*i] = t.x; v[4*i+1] = t.y; v[4*i+2] = t.z; v[4*i+3] = t.w;
            s += t.x + t.y + t.z + t.w;
            ss += t.x*t.x + t.y*t.y + t.z*t.z + t.w*t.w;
        }
        #pragma unroll
        for (int m = 1; m < 8; m <<= 1){ s += __shfl_xor(s, m); ss += __shfl_xor(ss, m); }
        float mu = s * (1.f/192.f), var = ss * (1.f/192.f) - mu*mu, rs = rsqrtf(var + 1e-5f);
        #pragma unroll
        for (int i = 0; i < 3; i++){
            bf16x8 t;
            #pragma unroll
            for (int jj = 0; jj < 8; jj++){
                int c = sub*24 + 8*i + jj;
                t[jj] = (__bf16)((v[8*i+jj] - mu) * rs * g1[c] + b1v[c]);
            }
            *(bf16x8*)&Qs[row][sub*24 + 8*i] = t;
        }
    }
    __syncthreads();
    {   // KVproj: KV^T = Wkv^T @ xln^T ; waves 0-3 -> K rows, 4-7 -> V^T
        const int ct = w & 3, rh = w >> 2;
        const int tok = ct * 16 + (lane & 15);
        bf16x8 bfr[6];
        #pragma unroll
        for (int kt = 0; kt < 6; kt++) bfr[kt] = *(const bf16x8*)&Qs[tok][kt*32 + (lane>>4)*8];
        #pragma unroll
        for (int i = 0; i < 12; i++){
            int rt = rh * 12 + i;
            f32x4 acc = {0.f,0.f,0.f,0.f};
            #pragma unroll
            for (int kt = 0; kt < 6; kt++) acc = MFMA16(afrag(wsw + WKV_OFF, 24, kt, rt, lane), bfr[kt], acc);
            int cb = rt * 16 + ((lane >> 4) << 2);
            float4 b4 = *(const float4*)&bkv[cb];
            acc[0] += b4.x; acc[1] += b4.y; acc[2] += b4.z; acc[3] += b4.w;
            if (cb < 192){
                bf16x4 t;
                #pragma unroll
                for (int r = 0; r < 4; r++) t[r] = (__bf16)acc[r];
                *(bf16x4*)&Ks[tok][cb] = t;
            } else {
                #pragma unroll
                for (int r = 0; r < 4; r++) Vt[cb - 192 + r][tok] = (__bf16)acc[r];
            }
        }
    }
    __syncthreads();

    const int li_ = lane & 15, gt_ = lane >> 4, rsel = lane >> 5;
    const int ctQ = w & 3, rhQ = w >> 2;
    const int qlQ = ctQ * 16 + li_;

    // Qproj(qt): Q^T = Wq^T(scaled) @ xd^T -> Qs (overwrites xln/old Q)
    auto qproj = [&](int qt){
        const int ft = ((b * 32 + 8 * sw_ + qt) * 64 + 8 * hw_ + (qlQ >> 3)) * 64 + 8 * ww_ + (qlQ & 7);
        bf16x8 bfr[3];
        #pragma unroll
        for (int kt = 0; kt < 3; kt++){
            const float* xp = xd + ft * 96 + kt * 32 + gt_ * 8;
            float4 t0 = *(const float4*)xp;
            float4 t1 = *(const float4*)(xp + 4);
            bf16x8 t;
            t[0]=(__bf16)t0.x; t[1]=(__bf16)t0.y; t[2]=(__bf16)t0.z; t[3]=(__bf16)t0.w;
            t[4]=(__bf16)t1.x; t[5]=(__bf16)t1.y; t[6]=(__bf16)t1.z; t[7]=(__bf16)t1.w;
            bfr[kt] = t;
        }
        #pragma unroll
        for (int i = 0; i < 6; i++){
            int rt = rhQ * 6 + i;
            f32x4 acc = {0.f,0.f,0.f,0.f};
            #pragma unroll
            for (int kt = 0; kt < 3; kt++) acc = MFMA16(afrag(wsw + WQ_OFF, 12, kt, rt, lane), bfr[kt], acc);
            int cb = rt * 16 + (gt_ << 2);
            float4 b4 = *(const float4*)&bq[cb];
            bf16x4 t;
            t[0] = (__bf16)(acc[0] + b4.x * ATT_SCALE);
            t[1] = (__bf16)(acc[1] + b4.y * ATT_SCALE);
            t[2] = (__bf16)(acc[2] + b4.z * ATT_SCALE);
            t[3] = (__bf16)(acc[3] + b4.w * ATT_SCALE);
            *(bf16x4*)&Qs[qlQ][cb] = t;
        }
    };

    // outproj(qt): y += Wp^T @ Os^T + bpj
    auto outproj = [&](int qt){
        const int ft = ((b * 32 + 8 * sw_ + qt) * 64 + 8 * hw_ + (qlQ >> 3)) * 64 + 8 * ww_ + (qlQ & 7);
        bf16x8 bfr[6];
        #pragma unroll
        for (int kt = 0; kt < 6; kt++) bfr[kt] = *(const bf16x8*)&Os[qlQ][kt*32 + gt_*8];
        #pragma unroll
        for (int i = 0; i < 3; i++){
            int rt = rhQ * 3 + i;
            f32x4 acc = {0.f,0.f,0.f,0.f};
            #pragma unroll
            for (int kt = 0; kt < 6; kt++) acc = MFMA16(afrag(wsw + WP_OFF, 6, kt, rt, lane), bfr[kt], acc);
            int cb = rt * 16 + (gt_ << 2);
            float4 b4 = *(const float4*)&bpj[cb];
            float4 old = *(const float4*)&yout[ft * 96 + cb];
            float4 res;
            res.x = old.x + acc[0] + b4.x;
            res.y = old.y + acc[1] + b4.y;
            res.z = old.z + acc[2] + b4.z;
            res.w = old.w + acc[3] + b4.w;
            *(float4*)&yout[ft * 96 + cb] = res;
        }
    };

    qproj(0);
    __syncthreads();

    for (int qt = 0; qt < 8; qt++){
        // ---- phase B: scores + softmax + P redistribution + PV -> Os ----
        #pragma unroll
        for (int ui = 0; ui < 3; ui++){
            const int u = w * 3 + ui;
            const int h = u >> 2, qct = u & 3;
            f32x4 sc[4];
            __builtin_amdgcn_s_setprio(1);
            #pragma unroll
            for (int rt = 0; rt < 4; rt++){
                bf16x8 a  = *(const bf16x8*)&Ks[rt*16 + li_][h*32 + gt_*8];
                bf16x8 bq8 = *(const bf16x8*)&Qs[qct*16 + li_][h*32 + gt_*8];
                f32x4 z = {0.f,0.f,0.f,0.f};
                sc[rt] = MFMA16(a, bq8, z);
            }
            __builtin_amdgcn_s_setprio(0);
            const int qg = qt * 64 + qct * 16 + li_;
            const float* bp = bias + (h * 512 + qg) * 64 + (gt_ << 2);
            #pragma unroll
            for (int rt = 0; rt < 4; rt++){
                float4 b4 = *(const float4*)(bp + rt * 16);
                sc[rt][0] += b4.x; sc[rt][1] += b4.y; sc[rt][2] += b4.z; sc[rt][3] += b4.w;
            }
            float m = sc[0][0];
            #pragma unroll
            for (int rt = 0; rt < 4; rt++)
                #pragma unroll
                for (int r = 0; r < 4; r++) m = fmaxf(m, sc[rt][r]);
            m = fmaxf(m, __shfl_xor(m, 16));
            m = fmaxf(m, __shfl_xor(m, 32));
            float sum = 0.f;
            #pragma unroll
            for (int rt = 0; rt < 4; rt++)
                #pragma unroll
                for (int r = 0; r < 4; r++){ float e = __expf(sc[rt][r] - m); sc[rt][r] = e; sum += e; }
            sum += __shfl_xor(sum, 16);
            sum += __shfl_xor(sum, 32);
            float inv = 1.f / sum;
            // pack normalized P into bf16 pair words
            unsigned pwv[4][2];
            #pragma unroll
            for (int rt = 0; rt < 4; rt++){
                union { __bf16 hh[2]; unsigned u; } c0, c1;
                c0.hh[0] = (__bf16)(sc[rt][0] * inv); c0.hh[1] = (__bf16)(sc[rt][1] * inv);
                c1.hh[0] = (__bf16)(sc[rt][2] * inv); c1.hh[1] = (__bf16)(sc[rt][3] * inv);
                pwv[rt][0] = c0.u; pwv[rt][1] = c1.u;
            }
            // redistribute C-frag -> B-frag layout
            unsigned bfw[2][4];
            #pragma unroll
            for (int kt = 0; kt < 2; kt++){
                #pragma unroll
                for (int t = 0; t < 4; t++){
                    int gs   = ((gt_ & 1) << 1) + (t >> 1);
                    int addr = (((gs << 4) + li_) << 2);
                    int w0 = __builtin_amdgcn_ds_bpermute(addr, (int)pwv[2*kt + 0][t & 1]);
                    int w1 = __builtin_amdgcn_ds_bpermute(addr, (int)pwv[2*kt + 1][t & 1]);
                    bfw[kt][t] = rsel ? (unsigned)w1 : (unsigned)w0;
                }
            }
            union { unsigned u[4]; bf16x8 v; } pb0, pb1;
            #pragma unroll
            for (int t = 0; t < 4; t++){ pb0.u[t] = bfw[0][t]; pb1.u[t] = bfw[1][t]; }
            __builtin_amdgcn_s_setprio(1);
            #pragma unroll
            for (int dt = 0; dt < 2; dt++){
                f32x4 o = {0.f,0.f,0.f,0.f};
                bf16x8 a0 = *(const bf16x8*)&Vt[h*32 + dt*16 + li_][gt_*8];
                bf16x8 a1 = *(const bf16x8*)&Vt[h*32 + dt*16 + li_][32 + gt_*8];
                o = MFMA16(a0, pb0.v, o);
                o = MFMA16(a1, pb1.v, o);
                // write attn-out tile directly to Os
                const int tok = qct * 16 + li_;
                int cb = h * 32 + dt * 16 + (gt_ << 2);
                bf16x4 t;
                #pragma unroll
                for (int r = 0; r < 4; r++) t[r] = (__bf16)o[r];
                *(bf16x4*)&Os[tok][cb] = t;
            }
            __builtin_amdgcn_s_setprio(0);
        }
        __syncthreads();
        // ---- phase A: outproj(qt) + Qproj(qt+1) ----
        outproj(qt);
        if (qt < 7) qproj(qt + 1);
        __syncthreads();
    }
}

// ---------------- MLP (MFMA): d_out = y + W2(gelu(W1 ln(y)+b1))+b2, in place ----------------
// hidden processed in 2 halves of 192 -> LDS 51.2 KB (proven round 5/7)
__global__ __launch_bounds__(512) void k_mlp(const float* __restrict__ y,
    const float* __restrict__ g2, const float* __restrict__ b2v,
    const __bf16* __restrict__ wsw, const float* __restrict__ b1m,
    const float* __restrict__ b2m, float* __restrict__ outp){
    __shared__ __bf16 yln[64][104];
    __shared__ __bf16 hsm[64][200];
    __shared__ __bf16 ybf[64][96];    // raw y stash for residual
    const int tid = threadIdx.x, lane = tid & 63, w = tid >> 6;
    const int t0 = blockIdx.x * 64;
    {   // LN stage
        int row = tid >> 3, sub = tid & 7;
        const float* yp = y + (t0 + row) * 96 + sub * 12;
        float v[12]; float s = 0.f, ss = 0.f;
        #pragma unroll
        for (int i = 0; i < 3; i++){
            float4 t = ((const float4*)yp)[i];
            v[4*i] = t.x; v[4*i+1] = t.y; v[4*i+2] = t.z; v[4*i+3] = t.w;
            s += t.x + t.y + t.z + t.w;
            ss += t.x*t.x + t.y*t.y + t.z*t.z + t.w*t.w;
        }
        #pragma unroll
        for (int i = 0; i < 3; i++){
            bf16x4 t;
            #pragma unroll
            for (int jj = 0; jj < 4; jj++) t[jj] = (__bf16)v[4*i+jj];
            *(bf16x4*)&ybf[row][sub*12 + 4*i] = t;
        }
        #pragma unroll
        for (int m = 1; m < 8; m <<= 1){ s += __shfl_xor(s, m); ss += __shfl_xor(ss, m); }
        float mu = s * (1.f/96.f), var = ss * (1.f/96.f) - mu*mu, rs = rsqrtf(var + 1e-5f);
        #pragma unroll
        for (int i = 0; i < 3; i++){
            bf16x4 t;
            #pragma unroll
            for (int jj = 0; jj < 4; jj++){
                int c = sub*12 + 4*i + jj;
                t[jj] = (__bf16)((v[4*i+jj] - mu) * rs * g2[c] + b2v[c]);
            }
            *(bf16x4*)&yln[row][sub*12 + 4*i] = t;
        }
    }
    __syncthreads();
    const int ct = w & 3, rh = w >> 2;
    const int tok = ct * 16 + (lane & 15);
    bf16x8 bfrY[3];
    #pragma unroll
    for (int kt = 0; kt < 3; kt++) bfrY[kt] = *(const bf16x8*)&yln[tok][kt*32 + (lane>>4)*8];
    f32x4 oacc[3];
    #pragma unroll
    for (int i = 0; i < 3; i++){ f32x4 z = {0.f,0.f,0.f,0.f}; oacc[i] = z; }

    #pragma unroll
    for (int hh = 0; hh < 2; hh++){
        // GEMM1 half: h^T = W1^T @ yln^T, gelu -> hsm
        #pragma unroll
        for (int i = 0; i < 6; i++){
            int rtl = rh * 6 + i;            // [0,12)
            int rtg = hh * 12 + rtl;
            f32x4 acc = {0.f,0.f,0.f,0.f};
            #pragma unroll
            for (int kt = 0; kt < 3; kt++) acc = MFMA16(afrag(wsw + W1_OFF, 24, kt, rtg, lane), bfrY[kt], acc);
            int cb = rtl * 16 + ((lane >> 4) << 2);
            float4 b4 = *(const float4*)&b1m[hh * 192 + cb];
            bf16x4 t;
            t[0] = (__bf16)gelu_exact(acc[0] + b4.x);
            t[1] = (__bf16)gelu_exact(acc[1] + b4.y);
            t[2] = (__bf16)gelu_exact(acc[2] + b4.z);
            t[3] = (__bf16)gelu_exact(acc[3] + b4.w);
            *(bf16x4*)&hsm[tok][cb] = t;
        }
        __syncthreads();
        // GEMM2 half: accumulate o^T += W2half^T @ h^T
        bf16x8 bfrH[6];
        #pragma unroll
        for (int kt = 0; kt < 6; kt++) bfrH[kt] = *(const bf16x8*)&hsm[tok][kt*32 + (lane>>4)*8];
        #pragma unroll
        for (int i = 0; i < 3; i++){
            int rt = rh * 3 + i;
            #pragma unroll
            for (int kt = 0; kt < 6; kt++)
                oacc[i] = MFMA16(afrag(wsw + W2_OFF, 6, hh * 6 + kt, rt, lane), bfrH[kt], oacc[i]);
        }
        __syncthreads();
    }
    #pragma unroll
    for (int i = 0; i < 3; i++){
        int rt = rh * 3 + i;
        int cb = rt * 16 + ((lane >> 4) << 2);
        float4 b4 = *(const float4*)&b2m[cb];
        bf16x4 yv = *(const bf16x4*)&ybf[tok][cb];
        float4 res;
        res.x = (float)yv[0] + oacc[i][0] + b4.x;
        res.y = (float)yv[1] + oacc[i][1] + b4.y;
        res.z = (float)yv[2] + oacc[i][2] + b4.z;
        res.w = (float)yv[3] + oacc[i][3] + b4.w;
        *(float4*)&outp[(t0 + tok) * 96 + cb] = res;
    }
}

extern "C" void kernel_launch(void* const* d_in, const int* in_sizes, int n_in,
                              void* d_out, int out_size, void* d_ws, size_t ws_size,
                              hipStream_t stream){
    const float* x    = (const float*)d_in[0];
    const float* xd   = (const float*)d_in[1];
    const float* g1   = (const float*)d_in[2];
    const float* b1v  = (const float*)d_in[3];
    const float* Wkv  = (const float*)d_in[4];
    const float* bkv  = (const float*)d_in[5];
    const float* Wq   = (const float*)d_in[6];
    const float* bq   = (const float*)d_in[7];
    const float* Wp   = (const float*)d_in[8];
    const float* bpj  = (const float*)d_in[9];
    const float* btab = (const float*)d_in[10];
    const float* eg   = (const float*)d_in[11];
    const float* eb   = (const float*)d_in[12];
    const float* dw   = (const float*)d_in[13];
    const float* db   = (const float*)d_in[14];
    const float* g2   = (const float*)d_in[15];
    const float* b2v  = (const float*)d_in[16];
    const float* W1   = (const float*)d_in[17];
    const float* b1m  = (const float*)d_in[18];
    const float* W2   = (const float*)d_in[19];
    const float* b2m  = (const float*)d_in[20];
    (void)in_sizes; (void)n_in; (void)out_size; (void)ws_size;

    float*   out  = (float*)d_out;
    float*   bias = (float*)d_ws;
    __bf16*  wsw  = (__bf16*)((char*)d_ws + BIAS_BYTES);

    k_prep  <<<2064, 256, 0, stream>>>(btab, Wkv, Wq, Wp, dw, W1, W2, bias, wsw);
    k_deconv<<<512, 512, 0, stream>>>(x, eg, eb, wsw, db, out);
    k_attn  <<<512, 512, 0, stream>>>(x, xd, g1, b1v, bkv, bq, bpj, wsw, bias, out);
    k_mlp   <<<4096, 512, 0, stream>>>(out, g2, b2v, wsw, b1m, b2m, out);
}

// Round 9
// 320.811 us; speedup vs baseline: 1.2829x; 1.0238x over previous
//
#include <hip/hip_runtime.h>
#include <math.h>

#define ATT_SCALE 0.17677669529663687f  // 32^-0.5

typedef __bf16 bf16x8 __attribute__((ext_vector_type(8)));
typedef __bf16 bf16x4 __attribute__((ext_vector_type(4)));
typedef float  f32x4  __attribute__((ext_vector_type(4)));

#define MFMA16(a,b,c) __builtin_amdgcn_mfma_f32_16x16x32_bf16(a,b,c,0,0,0)

// ws layout: [0,786432) f32 expanded bias; then bf16 swizzled weights
#define BIAS_BYTES 786432
#define WKV_OFF 0        // 192x384  kt6  NRT24
#define WQ_OFF  73728    // 96x192   kt3  NRT12 (pre-scaled)
#define WP_OFF  92160    // 192x96   kt6  NRT6
#define WD_OFF  110592   // deconv: [ii2][kt6][rt24][lane][8], rows m = jk*96+o
#define W1_OFF  258048   // 96x384   kt3  NRT24
#define W2_OFF  294912   // 384x96   kt12 NRT6
#define NSWZ    331776

static __device__ __forceinline__ float gelu_exact(float v){
    return 0.5f * v * (1.0f + erff(v * 0.70710678118654752f));
}

static __device__ __forceinline__ bf16x8 afrag(const __bf16* w, int NRT, int kt, int rt, int lane){
    return ((const bf16x8*)w)[(kt*NRT + rt)*64 + lane];
}

// ---------------- prep: bias expand + weight bf16 swizzle ----------------
__global__ __launch_bounds__(256) void k_prep(const float* __restrict__ table,
    const float* __restrict__ Wkv, const float* __restrict__ Wq,
    const float* __restrict__ Wp,  const float* __restrict__ Wd,
    const float* __restrict__ W1,  const float* __restrict__ W2,
    float* __restrict__ bias, __bf16* __restrict__ wsw){
    int id = blockIdx.x * 256 + threadIdx.x;
    if (id < 196608){
        int k  = id & 63;
        int qg = (id >> 6) & 511;
        int h  = id >> 15;
        int qi = qg >> 6, qj = (qg >> 3) & 7, qk = qg & 7;
        int ki = k >> 4,  kj = (k >> 2) & 3,  kk = k & 3;
        int r0 = (qi >> 1) - ki + 3;
        int r1 = (qj >> 1) - kj + 3;
        int r2 = (qk >> 1) - kk + 3;
        bias[id] = table[((r0 * 7 + r1) * 7 + r2) * 6 + h];
        return;
    }
    id -= 196608;
    if (id >= NSWZ) return;
    if (id >= WD_OFF && id < W1_OFF){
        // deconv weights: rows m = jk*96+o, split by ii (proven r8)
        int lid  = id - WD_OFF;                    // [0, 147456)
        int j    = lid & 7, lane = (lid >> 3) & 63, tile = lid >> 9;  // tile in [0,288)
        int rt   = tile % 24;
        int kt2  = tile / 24;                      // ii*6 + kt
        int ii   = kt2 / 6, kt = kt2 % 6;
        int n    = rt * 16 + (lane & 15);          // m-index
        int o    = n % 96, jk = n / 96;
        int kdim = kt * 32 + (lane >> 4) * 8 + j;
        wsw[id] = (__bf16)(Wd[(kdim * 96 + o) * 8 + ii * 4 + jk]);
        return;
    }
    const float* W; int N, NRT, off; float sc = 1.f;
    if      (id < WQ_OFF){ W = Wkv; N = 384; NRT = 24; off = WKV_OFF; }
    else if (id < WP_OFF){ W = Wq;  N = 192; NRT = 12; off = WQ_OFF; sc = ATT_SCALE; }
    else if (id < WD_OFF){ W = Wp;  N = 96;  NRT = 6;  off = WP_OFF; }
    else if (id < W2_OFF){ W = W1;  N = 384; NRT = 24; off = W1_OFF; }
    else                 { W = W2;  N = 96;  NRT = 6;  off = W2_OFF; }
    int lid  = id - off;
    int j    = lid & 7, lane = (lid >> 3) & 63, tile = lid >> 9;
    int rt   = tile % NRT, kt = tile / NRT;
    int n    = rt * 16 + (lane & 15);
    int k    = kt * 32 + (lane >> 4) * 8 + j;
    wsw[id + 0] = (__bf16)(W[k * N + n] * sc);
}

// ---------------- deconv path (MFMA): d_out = sc (full overwrite), float4 stores (proven r8) ----------------
__global__ __launch_bounds__(512) void k_deconv(const float* __restrict__ x,
    const float* __restrict__ eg, const float* __restrict__ eb,
    const __bf16* __restrict__ wsw, const float* __restrict__ db,
    float* __restrict__ out){
    __shared__ __bf16 xe[64][200];
    const int tid = threadIdx.x, lane = tid & 63, w = tid >> 6;
    const int ci0 = blockIdx.x * 64;
    {   // LN stage -> bf16
        int row = tid >> 3, sub = tid & 7;
        const float* xp = x + (ci0 + row) * 192 + sub * 24;
        float v[24]; float s = 0.f, ss = 0.f;
        #pragma unroll
        for (int i = 0; i < 6; i++){
            float4 t = ((const float4*)xp)[i];
            v[4*i] = t.x; v[4*i+1] = t.y; v[4*i+2] = t.z; v[4*i+3] = t.w;
            s += t.x + t.y + t.z + t.w;
            ss += t.x*t.x + t.y*t.y + t.z*t.z + t.w*t.w;
        }
        #pragma unroll
        for (int m = 1; m < 8; m <<= 1){ s += __shfl_xor(s, m); ss += __shfl_xor(ss, m); }
        float mu = s * (1.f/192.f), var = ss * (1.f/192.f) - mu*mu, rs = rsqrtf(var + 1e-5f);
        #pragma unroll
        for (int i = 0; i < 3; i++){
            bf16x8 t;
            #pragma unroll
            for (int jj = 0; jj < 8; jj++){
                int c = sub*24 + 8*i + jj;
                t[jj] = (__bf16)((v[8*i+jj] - mu) * rs * eg[c] + eb[c]);
            }
            *(bf16x8*)&xe[row][sub*24 + 8*i] = t;
        }
    }
    __syncthreads();
    const int li = lane & 15, gt = lane >> 4;
    const int ct = w & 3, ii = w >> 2;          // 4 token-tiles x 2 deconv-i halves
    const int tok = ct * 16 + li;
    const int ci  = ci0 + tok;
    const int bb  = ci >> 14, rem = ci & 16383;
    const int sC  = rem >> 10, hC = (rem >> 5) & 31, wC = rem & 31;
    const int ftb = ((bb * 32 + 2 * sC) * 64 + 2 * hC) * 64 + 2 * wC + ii * 4096;
    bf16x8 bfr[6];
    #pragma unroll
    for (int kt = 0; kt < 6; kt++) bfr[kt] = *(const bf16x8*)&xe[tok][kt*32 + gt*8];
    const __bf16* wd = wsw + WD_OFF + ii * 73728;
    for (int rt = 0; rt < 24; rt++){
        f32x4 acc = {0.f,0.f,0.f,0.f};
        #pragma unroll
        for (int kt = 0; kt < 6; kt++) acc = MFMA16(afrag(wd, 24, kt, rt, lane), bfr[kt], acc);
        int m  = rt * 16 + (gt << 2);
        int jk = m / 96, o = m - jk * 96;
        int ft = ftb + (jk >> 1) * 64 + (jk & 1);
        float4 d4 = *(const float4*)&db[o];
        float4 res;
        res.x = acc[0] + d4.x; res.y = acc[1] + d4.y;
        res.z = acc[2] + d4.z; res.w = acc[3] + d4.w;
        *(float4*)&out[ft * 96 + o] = res;
    }
}

// ---------------- fused windowed cross-attention (MFMA): d_out += attn ----------------
// proven r7 structure: LDS 74.5 KB, 4 phases/q-tile, ds_bpermute P redistribution, setprio
__global__ __launch_bounds__(512) void k_attn(const float* __restrict__ x,
    const float* __restrict__ xd, const float* __restrict__ g1, const float* __restrict__ b1v,
    const float* __restrict__ bkv, const float* __restrict__ bq, const float* __restrict__ bpj,
    const __bf16* __restrict__ wsw, const float* __restrict__ bias, float* __restrict__ yout){
    __shared__ __bf16 Qs[64][196];   // xln -> Q -> attn-out (aliased phases)
    __shared__ __bf16 Ks[64][196];
    __shared__ __bf16 Vt[192][68];   // V transposed [d][kv]
    const int tid = threadIdx.x, lane = tid & 63, w = tid >> 6;
    const int win = blockIdx.x, b = win >> 8, wrem = win & 255;
    const int sw_ = wrem >> 6, hw_ = (wrem >> 3) & 7, ww_ = wrem & 7;

    {   // LN stage of coarse x window -> Qs (as xln)
        int row = tid >> 3, sub = tid & 7;
        int si = row >> 4, hi = (row >> 2) & 3, wi = row & 3;
        int ci = ((b * 16 + 4 * sw_ + si) * 32 + 4 * hw_ + hi) * 32 + 4 * ww_ + wi;
        const float* xp = x + ci * 192 + sub * 24;
        float v[24]; float s = 0.f, ss = 0.f;
        #pragma unroll
        for (int i = 0; i < 6; i++){
            float4 t = ((const float4*)xp)[i];
            v[4*i] = t.x; v[4*i+1] = t.y; v[4*i+2] = t.z; v[4*i+3] = t.w;
            s += t.x + t.y + t.z + t.w;
            ss += t.x*t.x + t.y*t.y + t.z*t.z + t.w*t.w;
        }
        #pragma unroll
        for (int m = 1; m < 8; m <<= 1){ s += __shfl_xor(s, m); ss += __shfl_xor(ss, m); }
        float mu = s * (1.f/192.f), var = ss * (1.f/192.f) - mu*mu, rs = rsqrtf(var + 1e-5f);
        #pragma unroll
        for (int i = 0; i < 3; i++){
            bf16x8 t;
            #pragma unroll
            for (int jj = 0; jj < 8; jj++){
                int c = sub*24 + 8*i + jj;
                t[jj] = (__bf16)((v[8*i+jj] - mu) * rs * g1[c] + b1v[c]);
            }
            *(bf16x8*)&Qs[row][sub*24 + 8*i] = t;
        }
    }
    __syncthreads();
    {   // KVproj: KV^T = Wkv^T @ xln^T ; waves 0-3 -> K rows, 4-7 -> V^T
        const int ct = w & 3, rh = w >> 2;
        const int tok = ct * 16 + (lane & 15);
        bf16x8 bfr[6];
        #pragma unroll
        for (int kt = 0; kt < 6; kt++) bfr[kt] = *(const bf16x8*)&Qs[tok][kt*32 + (lane>>4)*8];
        #pragma unroll
        for (int i = 0; i < 12; i++){
            int rt = rh * 12 + i;
            f32x4 acc = {0.f,0.f,0.f,0.f};
            #pragma unroll
            for (int kt = 0; kt < 6; kt++) acc = MFMA16(afrag(wsw + WKV_OFF, 24, kt, rt, lane), bfr[kt], acc);
            int cb = rt * 16 + ((lane >> 4) << 2);
            float4 b4 = *(const float4*)&bkv[cb];
            acc[0] += b4.x; acc[1] += b4.y; acc[2] += b4.z; acc[3] += b4.w;
            if (cb < 192){
                bf16x4 t;
                #pragma unroll
                for (int r = 0; r < 4; r++) t[r] = (__bf16)acc[r];
                *(bf16x4*)&Ks[tok][cb] = t;
            } else {
                #pragma unroll
                for (int r = 0; r < 4; r++) Vt[cb - 192 + r][tok] = (__bf16)acc[r];
            }
        }
    }
    __syncthreads();

    const int li_ = lane & 15, gt_ = lane >> 4, rsel = lane >> 5;

    for (int qt = 0; qt < 8; qt++){
        {   // Qproj: Q^T = Wq^T(scaled) @ xd^T ; B-frags straight from global f32
            const int ct = w & 3, rh = w >> 2;
            const int ql = ct * 16 + (lane & 15);
            const int ft = ((b * 32 + 8 * sw_ + qt) * 64 + 8 * hw_ + (ql >> 3)) * 64 + 8 * ww_ + (ql & 7);
            bf16x8 bfr[3];
            #pragma unroll
            for (int kt = 0; kt < 3; kt++){
                const float* xp = xd + ft * 96 + kt * 32 + (lane >> 4) * 8;
                float4 t0 = *(const float4*)xp;
                float4 t1 = *(const float4*)(xp + 4);
                bf16x8 t;
                t[0]=(__bf16)t0.x; t[1]=(__bf16)t0.y; t[2]=(__bf16)t0.z; t[3]=(__bf16)t0.w;
                t[4]=(__bf16)t1.x; t[5]=(__bf16)t1.y; t[6]=(__bf16)t1.z; t[7]=(__bf16)t1.w;
                bfr[kt] = t;
            }
            #pragma unroll
            for (int i = 0; i < 6; i++){
                int rt = rh * 6 + i;
                f32x4 acc = {0.f,0.f,0.f,0.f};
                #pragma unroll
                for (int kt = 0; kt < 3; kt++) acc = MFMA16(afrag(wsw + WQ_OFF, 12, kt, rt, lane), bfr[kt], acc);
                int cb = rt * 16 + ((lane >> 4) << 2);
                float4 b4 = *(const float4*)&bq[cb];
                bf16x4 t;
                t[0] = (__bf16)(acc[0] + b4.x * ATT_SCALE);
                t[1] = (__bf16)(acc[1] + b4.y * ATT_SCALE);
                t[2] = (__bf16)(acc[2] + b4.z * ATT_SCALE);
                t[3] = (__bf16)(acc[3] + b4.w * ATT_SCALE);
                *(bf16x4*)&Qs[ql][cb] = t;
            }
        }
        __syncthreads();
        // scores + softmax + in-register P redistribution + PV
        f32x4 ov[3][2];
        #pragma unroll
        for (int ui = 0; ui < 3; ui++){
            const int u = w * 3 + ui;
            const int h = u >> 2, qct = u & 3;
            f32x4 sc[4];
            __builtin_amdgcn_s_setprio(1);
            #pragma unroll
            for (int rt = 0; rt < 4; rt++){
                bf16x8 a  = *(const bf16x8*)&Ks[rt*16 + li_][h*32 + gt_*8];
                bf16x8 bq8 = *(const bf16x8*)&Qs[qct*16 + li_][h*32 + gt_*8];
                f32x4 z = {0.f,0.f,0.f,0.f};
                sc[rt] = MFMA16(a, bq8, z);
            }
            __builtin_amdgcn_s_setprio(0);
            const int qg = qt * 64 + qct * 16 + li_;
            const float* bp = bias + (h * 512 + qg) * 64 + (gt_ << 2);
            #pragma unroll
            for (int rt = 0; rt < 4; rt++){
                float4 b4 = *(const float4*)(bp + rt * 16);
                sc[rt][0] += b4.x; sc[rt][1] += b4.y; sc[rt][2] += b4.z; sc[rt][3] += b4.w;
            }
            float m = sc[0][0];
            #pragma unroll
            for (int rt = 0; rt < 4; rt++)
                #pragma unroll
                for (int r = 0; r < 4; r++) m = fmaxf(m, sc[rt][r]);
            m = fmaxf(m, __shfl_xor(m, 16));
            m = fmaxf(m, __shfl_xor(m, 32));
            float sum = 0.f;
            #pragma unroll
            for (int rt = 0; rt < 4; rt++)
                #pragma unroll
                for (int r = 0; r < 4; r++){ float e = __expf(sc[rt][r] - m); sc[rt][r] = e; sum += e; }
            sum += __shfl_xor(sum, 16);
            sum += __shfl_xor(sum, 32);
            float inv = 1.f / sum;
            // pack normalized P into bf16 pair words: pwv[rt][h2] covers kv = rt*16+gt*4+2*h2+{0,1}
            unsigned pwv[4][2];
            #pragma unroll
            for (int rt = 0; rt < 4; rt++){
                union { __bf16 hh[2]; unsigned u; } c0, c1;
                c0.hh[0] = (__bf16)(sc[rt][0] * inv); c0.hh[1] = (__bf16)(sc[rt][1] * inv);
                c1.hh[0] = (__bf16)(sc[rt][2] * inv); c1.hh[1] = (__bf16)(sc[rt][3] * inv);
                pwv[rt][0] = c0.u; pwv[rt][1] = c1.u;
            }
            // redistribute C-frag -> B-frag layout: word t of kt comes from lane gs*16+li,
            // tile rt_s = 2kt + rsel, pair h2 = t&1, gs = 2*(gt&1) + (t>>1)
            unsigned bfw[2][4];
            #pragma unroll
            for (int kt = 0; kt < 2; kt++){
                #pragma unroll
                for (int t = 0; t < 4; t++){
                    int gs   = ((gt_ & 1) << 1) + (t >> 1);
                    int addr = (((gs << 4) + li_) << 2);
                    int w0 = __builtin_amdgcn_ds_bpermute(addr, (int)pwv[2*kt + 0][t & 1]);
                    int w1 = __builtin_amdgcn_ds_bpermute(addr, (int)pwv[2*kt + 1][t & 1]);
                    bfw[kt][t] = rsel ? (unsigned)w1 : (unsigned)w0;
                }
            }
            union { unsigned u[4]; bf16x8 v; } pb0, pb1;
            #pragma unroll
            for (int t = 0; t < 4; t++){ pb0.u[t] = bfw[0][t]; pb1.u[t] = bfw[1][t]; }
            __builtin_amdgcn_s_setprio(1);
            #pragma unroll
            for (int dt = 0; dt < 2; dt++){
                f32x4 o = {0.f,0.f,0.f,0.f};
                bf16x8 a0 = *(const bf16x8*)&Vt[h*32 + dt*16 + li_][gt_*8];
                bf16x8 a1 = *(const bf16x8*)&Vt[h*32 + dt*16 + li_][32 + gt_*8];
                o = MFMA16(a0, pb0.v, o);
                o = MFMA16(a1, pb1.v, o);
                ov[ui][dt] = o;
            }
            __builtin_amdgcn_s_setprio(0);
        }
        __syncthreads();   // all Qs reads done
        #pragma unroll
        for (int ui = 0; ui < 3; ui++){
            const int u = w * 3 + ui;
            const int h = u >> 2, qct = u & 3;
            const int tok = qct * 16 + li_;
            #pragma unroll
            for (int dt = 0; dt < 2; dt++){
                int cb = h * 32 + dt * 16 + (gt_ << 2);
                bf16x4 t;
                #pragma unroll
                for (int r = 0; r < 4; r++) t[r] = (__bf16)ov[ui][dt][r];
                *(bf16x4*)&Qs[tok][cb] = t;
            }
        }
        __syncthreads();
        {   // outproj: Y^T = Wp^T @ out^T ; += into d_out (y = sc + attn)
            const int ct = w & 3, rh = w >> 2;
            const int ql = ct * 16 + (lane & 15);
            const int ft = ((b * 32 + 8 * sw_ + qt) * 64 + 8 * hw_ + (ql >> 3)) * 64 + 8 * ww_ + (ql & 7);
            bf16x8 bfr[6];
            #pragma unroll
            for (int kt = 0; kt < 6; kt++) bfr[kt] = *(const bf16x8*)&Qs[ql][kt*32 + (lane>>4)*8];
            #pragma unroll
            for (int i = 0; i < 3; i++){
                int rt = rh * 3 + i;
                f32x4 acc = {0.f,0.f,0.f,0.f};
                #pragma unroll
                for (int kt = 0; kt < 6; kt++) acc = MFMA16(afrag(wsw + WP_OFF, 6, kt, rt, lane), bfr[kt], acc);
                int cb = rt * 16 + ((lane >> 4) << 2);
                float4 b4 = *(const float4*)&bpj[cb];
                float4 old = *(const float4*)&yout[ft * 96 + cb];
                float4 res;
                res.x = old.x + acc[0] + b4.x;
                res.y = old.y + acc[1] + b4.y;
                res.z = old.z + acc[2] + b4.z;
                res.w = old.w + acc[3] + b4.w;
                *(float4*)&yout[ft * 96 + cb] = res;
            }
        }
        __syncthreads();   // before next qt overwrites Qs
    }
}

// ---------------- MLP (MFMA): d_out = y + W2(gelu(W1 ln(y)+b1))+b2, in place ----------------
// hidden processed in 2 halves of 192 -> LDS 51.2 KB (proven round 5/7/8)
__global__ __launch_bounds__(512) void k_mlp(const float* __restrict__ y,
    const float* __restrict__ g2, const float* __restrict__ b2v,
    const __bf16* __restrict__ wsw, const float* __restrict__ b1m,
    const float* __restrict__ b2m, float* __restrict__ outp){
    __shared__ __bf16 yln[64][104];
    __shared__ __bf16 hsm[64][200];
    __shared__ __bf16 ybf[64][96];    // raw y stash for residual
    const int tid = threadIdx.x, lane = tid & 63, w = tid >> 6;
    const int t0 = blockIdx.x * 64;
    {   // LN stage
        int row = tid >> 3, sub = tid & 7;
        const float* yp = y + (t0 + row) * 96 + sub * 12;
        float v[12]; float s = 0.f, ss = 0.f;
        #pragma unroll
        for (int i = 0; i < 3; i++){
            float4 t = ((const float4*)yp)[i];
            v[4*i] = t.x; v[4*i+1] = t.y; v[4*i+2] = t.z; v[4*i+3] = t.w;
            s += t.x + t.y + t.z + t.w;
            ss += t.x*t.x + t.y*t.y + t.z*t.z + t.w*t.w;
        }
        #pragma unroll
        for (int i = 0; i < 3; i++){
            bf16x4 t;
            #pragma unroll
            for (int jj = 0; jj < 4; jj++) t[jj] = (__bf16)v[4*i+jj];
            *(bf16x4*)&ybf[row][sub*12 + 4*i] = t;
        }
        #pragma unroll
        for (int m = 1; m < 8; m <<= 1){ s += __shfl_xor(s, m); ss += __shfl_xor(ss, m); }
        float mu = s * (1.f/96.f), var = ss * (1.f/96.f) - mu*mu, rs = rsqrtf(var + 1e-5f);
        #pragma unroll
        for (int i = 0; i < 3; i++){
            bf16x4 t;
            #pragma unroll
            for (int jj = 0; jj < 4; jj++){
                int c = sub*12 + 4*i + jj;
                t[jj] = (__bf16)((v[4*i+jj] - mu) * rs * g2[c] + b2v[c]);
            }
            *(bf16x4*)&yln[row][sub*12 + 4*i] = t;
        }
    }
    __syncthreads();
    const int ct = w & 3, rh = w >> 2;
    const int tok = ct * 16 + (lane & 15);
    bf16x8 bfrY[3];
    #pragma unroll
    for (int kt = 0; kt < 3; kt++) bfrY[kt] = *(const bf16x8*)&yln[tok][kt*32 + (lane>>4)*8];
    f32x4 oacc[3];
    #pragma unroll
    for (int i = 0; i < 3; i++){ f32x4 z = {0.f,0.f,0.f,0.f}; oacc[i] = z; }

    #pragma unroll
    for (int hh = 0; hh < 2; hh++){
        // GEMM1 half: h^T = W1^T @ yln^T, gelu -> hsm
        #pragma unroll
        for (int i = 0; i < 6; i++){
            int rtl = rh * 6 + i;            // [0,12)
            int rtg = hh * 12 + rtl;
            f32x4 acc = {0.f,0.f,0.f,0.f};
            #pragma unroll
            for (int kt = 0; kt < 3; kt++) acc = MFMA16(afrag(wsw + W1_OFF, 24, kt, rtg, lane), bfrY[kt], acc);
            int cb = rtl * 16 + ((lane >> 4) << 2);
            float4 b4 = *(const float4*)&b1m[hh * 192 + cb];
            bf16x4 t;
            t[0] = (__bf16)gelu_exact(acc[0] + b4.x);
            t[1] = (__bf16)gelu_exact(acc[1] + b4.y);
            t[2] = (__bf16)gelu_exact(acc[2] + b4.z);
            t[3] = (__bf16)gelu_exact(acc[3] + b4.w);
            *(bf16x4*)&hsm[tok][cb] = t;
        }
        __syncthreads();
        // GEMM2 half: accumulate o^T += W2half^T @ h^T
        bf16x8 bfrH[6];
        #pragma unroll
        for (int kt = 0; kt < 6; kt++) bfrH[kt] = *(const bf16x8*)&hsm[tok][kt*32 + (lane>>4)*8];
        #pragma unroll
        for (int i = 0; i < 3; i++){
            int rt = rh * 3 + i;
            #pragma unroll
            for (int kt = 0; kt < 6; kt++)
                oacc[i] = MFMA16(afrag(wsw + W2_OFF, 6, hh * 6 + kt, rt, lane), bfrH[kt], oacc[i]);
        }
        __syncthreads();
    }
    #pragma unroll
    for (int i = 0; i < 3; i++){
        int rt = rh * 3 + i;
        int cb = rt * 16 + ((lane >> 4) << 2);
        float4 b4 = *(const float4*)&b2m[cb];
        bf16x4 yv = *(const bf16x4*)&ybf[tok][cb];
        float4 res;
        res.x = (float)yv[0] + oacc[i][0] + b4.x;
        res.y = (float)yv[1] + oacc[i][1] + b4.y;
        res.z = (float)yv[2] + oacc[i][2] + b4.z;
        res.w = (float)yv[3] + oacc[i][3] + b4.w;
        *(float4*)&outp[(t0 + tok) * 96 + cb] = res;
    }
}

extern "C" void kernel_launch(void* const* d_in, const int* in_sizes, int n_in,
                              void* d_out, int out_size, void* d_ws, size_t ws_size,
                              hipStream_t stream){
    const float* x    = (const float*)d_in[0];
    const float* xd   = (const float*)d_in[1];
    const float* g1   = (const float*)d_in[2];
    const float* b1v  = (const float*)d_in[3];
    const float* Wkv  = (const float*)d_in[4];
    const float* bkv  = (const float*)d_in[5];
    const float* Wq   = (const float*)d_in[6];
    const float* bq   = (const float*)d_in[7];
    const float* Wp   = (const float*)d_in[8];
    const float* bpj  = (const float*)d_in[9];
    const float* btab = (const float*)d_in[10];
    const float* eg   = (const float*)d_in[11];
    const float* eb   = (const float*)d_in[12];
    const float* dw   = (const float*)d_in[13];
    const float* db   = (const float*)d_in[14];
    const float* g2   = (const float*)d_in[15];
    const float* b2v  = (const float*)d_in[16];
    const float* W1   = (const float*)d_in[17];
    const float* b1m  = (const float*)d_in[18];
    const float* W2   = (const float*)d_in[19];
    const float* b2m  = (const float*)d_in[20];
    (void)in_sizes; (void)n_in; (void)out_size; (void)ws_size;

    float*   out  = (float*)d_out;
    float*   bias = (float*)d_ws;
    __bf16*  wsw  = (__bf16*)((char*)d_ws + BIAS_BYTES);

    k_prep  <<<2064, 256, 0, stream>>>(btab, Wkv, Wq, Wp, dw, W1, W2, bias, wsw);
    k_deconv<<<512, 512, 0, stream>>>(x, eg, eb, wsw, db, out);
    k_attn  <<<512, 512, 0, stream>>>(x, xd, g1, b1v, bkv, bq, bpj, wsw, bias, out);
    k_mlp   <<<4096, 512, 0, stream>>>(out, g2, b2v, wsw, b1m, b2m, out);
}